// Round 1
// baseline (4603.107 us; speedup 1.0000x reference)
//
#include <hip/hip_runtime.h>
#include <math.h>

#define NN 100000
#define NE 3200000

// ---------------- degree / normalization ----------------

__global__ __launch_bounds__(256) void deg_kernel(const int* __restrict__ dst,
                                                  float* __restrict__ deg) {
    int tid = blockIdx.x * 256 + threadIdx.x;
    if (tid < NE) atomicAdd(&deg[dst[tid]], 1.0f);
}

__global__ __launch_bounds__(256) void dis_kernel(const float* __restrict__ deg,
                                                  float* __restrict__ dis) {
    int tid = blockIdx.x * 256 + threadIdx.x;
    if (tid < NN) dis[tid] = rsqrtf(deg[tid] + 1.0f);
}

// ---------------- matmul 1: [NN,128] @ [128,64] ----------------
// block = 256 (4 waves); each wave handles 4 nodes; W1 staged in LDS (32KB).
// lane: nsub = lane>>4 (node within wave), o4 = (lane&15)*4 (output quad).
__global__ __launch_bounds__(256) void mm1_kernel(const float* __restrict__ x,
                                                  const float* __restrict__ W,
                                                  float* __restrict__ y) {
    __shared__ float Ws[128 * 64];
    __shared__ float xs[4][4][132];  // +4 pad: nsub rows land on distinct banks
    int t = threadIdx.x;
    for (int i = t; i < 128 * 64; i += 256) Ws[i] = W[i];
    int wave = t >> 6, lane = t & 63;
    int nsub = lane >> 4;
    int o4 = (lane & 15) * 4;
    int base = blockIdx.x * 16 + wave * 4;  // 6250 blocks * 16 = 100000 exact
#pragma unroll
    for (int r = 0; r < 4; ++r) {
        xs[wave][r][lane] = x[(size_t)(base + r) * 128 + lane];
        xs[wave][r][lane + 64] = x[(size_t)(base + r) * 128 + 64 + lane];
    }
    __syncthreads();
    float4 acc = {0.f, 0.f, 0.f, 0.f};
#pragma unroll 16
    for (int k = 0; k < 128; ++k) {
        float a = xs[wave][nsub][k];
        const float4 w = *(const float4*)&Ws[k * 64 + o4];
        acc.x = fmaf(a, w.x, acc.x);
        acc.y = fmaf(a, w.y, acc.y);
        acc.z = fmaf(a, w.z, acc.z);
        acc.w = fmaf(a, w.w, acc.w);
    }
    *(float4*)&y[(size_t)(base + nsub) * 64 + o4] = acc;
}

// ---------------- matmul 2: [NN,64] @ [64,32] ----------------
// block = 256; each wave handles 8 nodes; nsub = lane>>3, o4 = (lane&7)*4.
__global__ __launch_bounds__(256) void mm2_kernel(const float* __restrict__ h,
                                                  const float* __restrict__ W,
                                                  float* __restrict__ y) {
    __shared__ float Ws[64 * 32];
    __shared__ float hs[4][8][68];  // +4 pad
    int t = threadIdx.x;
    for (int i = t; i < 64 * 32; i += 256) Ws[i] = W[i];
    int wave = t >> 6, lane = t & 63;
    int nsub = lane >> 3;
    int o4 = (lane & 7) * 4;
    int base = blockIdx.x * 32 + wave * 8;  // 3125 blocks * 32 = 100000 exact
#pragma unroll
    for (int r = 0; r < 8; ++r)
        hs[wave][r][lane] = h[(size_t)(base + r) * 64 + lane];
    __syncthreads();
    float4 acc = {0.f, 0.f, 0.f, 0.f};
#pragma unroll 16
    for (int k = 0; k < 64; ++k) {
        float a = hs[wave][nsub][k];
        const float4 w = *(const float4*)&Ws[k * 32 + o4];
        acc.x = fmaf(a, w.x, acc.x);
        acc.y = fmaf(a, w.y, acc.y);
        acc.z = fmaf(a, w.z, acc.z);
        acc.w = fmaf(a, w.w, acc.w);
    }
    *(float4*)&y[(size_t)(base + nsub) * 32 + o4] = acc;
}

// ---------------- edge aggregation (scatter-add) ----------------
// 16 threads per edge (64 feats as 4-float chunks). Coalesced 256B gather per edge.
__global__ __launch_bounds__(256) void agg64_kernel(const float* __restrict__ xw,
                                                    const float* __restrict__ dis,
                                                    const int* __restrict__ src,
                                                    const int* __restrict__ dst,
                                                    float* __restrict__ agg) {
    int tid = blockIdx.x * 256 + threadIdx.x;
    if (tid >= NE * 16) return;
    int e = tid >> 4, c = tid & 15;
    int s = src[e], d = dst[e];
    float nrm = dis[s] * dis[d];
    const float4 v = *(const float4*)&xw[(size_t)s * 64 + c * 4];
    float* ap = &agg[(size_t)d * 64 + c * 4];
    atomicAdd(ap + 0, v.x * nrm);
    atomicAdd(ap + 1, v.y * nrm);
    atomicAdd(ap + 2, v.z * nrm);
    atomicAdd(ap + 3, v.w * nrm);
}

// 8 threads per edge (32 feats).
__global__ __launch_bounds__(256) void agg32_kernel(const float* __restrict__ xw,
                                                    const float* __restrict__ dis,
                                                    const int* __restrict__ src,
                                                    const int* __restrict__ dst,
                                                    float* __restrict__ agg) {
    int tid = blockIdx.x * 256 + threadIdx.x;
    if (tid >= NE * 8) return;
    int e = tid >> 3, c = tid & 7;
    int s = src[e], d = dst[e];
    float nrm = dis[s] * dis[d];
    const float4 v = *(const float4*)&xw[(size_t)s * 32 + c * 4];
    float* ap = &agg[(size_t)d * 32 + c * 4];
    atomicAdd(ap + 0, v.x * nrm);
    atomicAdd(ap + 1, v.y * nrm);
    atomicAdd(ap + 2, v.z * nrm);
    atomicAdd(ap + 3, v.w * nrm);
}

// ---------------- epilogues ----------------
// h = relu(agg + dis^2 * xw + b), in-place into agg. 16 threads/node.
__global__ __launch_bounds__(256) void epi1_kernel(float* __restrict__ agg,
                                                   const float* __restrict__ xw,
                                                   const float* __restrict__ dis,
                                                   const float* __restrict__ b) {
    int tid = blockIdx.x * 256 + threadIdx.x;
    if (tid >= NN * 16) return;
    int n = tid >> 4, c = tid & 15;
    float ds = dis[n];
    float sl = ds * ds;
    float4 a = *(const float4*)&agg[(size_t)tid * 4];
    const float4 xv = *(const float4*)&xw[(size_t)tid * 4];
    const float4 bv = *(const float4*)&b[c * 4];
    a.x = fmaxf(a.x + sl * xv.x + bv.x, 0.f);
    a.y = fmaxf(a.y + sl * xv.y + bv.y, 0.f);
    a.z = fmaxf(a.z + sl * xv.z + bv.z, 0.f);
    a.w = fmaxf(a.w + sl * xv.w + bv.w, 0.f);
    *(float4*)&agg[(size_t)tid * 4] = a;
}

// z = agg + dis^2 * xw + b (no relu). 8 threads/node.
__global__ __launch_bounds__(256) void epi2_kernel(float* __restrict__ agg,
                                                   const float* __restrict__ xw,
                                                   const float* __restrict__ dis,
                                                   const float* __restrict__ b) {
    int tid = blockIdx.x * 256 + threadIdx.x;
    if (tid >= NN * 8) return;
    int n = tid >> 3, c = tid & 7;
    float ds = dis[n];
    float sl = ds * ds;
    float4 a = *(const float4*)&agg[(size_t)tid * 4];
    const float4 xv = *(const float4*)&xw[(size_t)tid * 4];
    const float4 bv = *(const float4*)&b[c * 4];
    a.x = a.x + sl * xv.x + bv.x;
    a.y = a.y + sl * xv.y + bv.y;
    a.z = a.z + sl * xv.z + bv.z;
    a.w = a.w + sl * xv.w + bv.w;
    *(float4*)&agg[(size_t)tid * 4] = a;
}

// ---------------- decode: sigmoid(dot(z[src], z[dst])) ----------------
// 32 lanes per edge: coalesced 128B row loads, shuffle reduce.
__global__ __launch_bounds__(256) void decode_kernel(const float* __restrict__ z,
                                                     const int* __restrict__ src,
                                                     const int* __restrict__ dst,
                                                     float* __restrict__ out) {
    int tid = blockIdx.x * 256 + threadIdx.x;
    int e = tid >> 5, k = tid & 31;
    if (e >= NE) return;
    int s = src[e], d = dst[e];
    float a = z[(size_t)s * 32 + k] * z[(size_t)d * 32 + k];
#pragma unroll
    for (int m = 16; m >= 1; m >>= 1) a += __shfl_xor(a, m, 32);
    if (k == 0) out[e] = 1.0f / (1.0f + expf(-a));
}

// ---------------- launcher ----------------

extern "C" void kernel_launch(void* const* d_in, const int* in_sizes, int n_in,
                              void* d_out, int out_size, void* d_ws, size_t ws_size,
                              hipStream_t stream) {
    const float* emb = (const float*)d_in[0];
    const float* W1  = (const float*)d_in[1];
    const float* b1  = (const float*)d_in[2];
    const float* W2  = (const float*)d_in[3];
    const float* b2  = (const float*)d_in[4];
    const int*   ei  = (const int*)d_in[5];
    const int* src = ei;
    const int* dst = ei + NE;
    float* out = (float*)d_out;

    // workspace layout (floats)
    const size_t NPAD = 100096;
    float* ws   = (float*)d_ws;
    float* deg  = ws;                 // NN
    float* dis  = ws + NPAD;          // NN
    float* bufA = dis + NPAD;         // 6.4M floats: xw1; later xw2 | agg2(z)
    float* bufB = bufA + (size_t)NN * 64;  // 6.4M floats: agg1 -> h (in place)
    float* xw1  = bufA;
    float* agg1 = bufB;               // becomes h
    float* xw2  = bufA;               // overlays dead xw1 (first 3.2M floats)
    float* agg2 = bufA + (size_t)NN * 32;  // overlays dead xw1 (second half); becomes z

    // zero accumulators (stream-ordered, graph-capture safe)
    hipMemsetAsync(deg, 0, NN * sizeof(float), stream);
    hipMemsetAsync(agg1, 0, (size_t)NN * 64 * sizeof(float), stream);

    deg_kernel<<<(NE + 255) / 256, 256, 0, stream>>>(dst, deg);
    dis_kernel<<<(NN + 255) / 256, 256, 0, stream>>>(deg, dis);

    // layer 1
    mm1_kernel<<<NN / 16, 256, 0, stream>>>(emb, W1, xw1);
    agg64_kernel<<<(NE * 16) / 256, 256, 0, stream>>>(xw1, dis, src, dst, agg1);
    epi1_kernel<<<(NN * 16 + 255) / 256, 256, 0, stream>>>(agg1, xw1, dis, b1);
    // agg1 now holds h; xw1 (bufA) is dead from here

    // layer 2
    hipMemsetAsync(agg2, 0, (size_t)NN * 32 * sizeof(float), stream);
    mm2_kernel<<<NN / 32, 256, 0, stream>>>(agg1 /*h*/, W2, xw2);
    agg32_kernel<<<(NE * 8) / 256, 256, 0, stream>>>(xw2, dis, src, dst, agg2);
    epi2_kernel<<<(NN * 8 + 255) / 256, 256, 0, stream>>>(agg2, xw2, dis, b2);
    // agg2 now holds z

    // decode
    decode_kernel<<<(NE * 32) / 256, 256, 0, stream>>>(agg2 /*z*/, src, dst, out);
}

// Round 2
// 1015.354 us; speedup vs baseline: 4.5335x; 4.5335x over previous
//
#include <hip/hip_runtime.h>
#include <math.h>

#define NN 100000
#define NE 3200000
#define NPAD 100096

// ---------------- degree count (in-degree by dst) ----------------
__global__ __launch_bounds__(256) void deg_kernel(const int* __restrict__ dst,
                                                  int* __restrict__ deg) {
    int tid = blockIdx.x * 256 + threadIdx.x;
    if (tid < NE) atomicAdd(&deg[dst[tid]], 1);
}

// ---------------- offsets: wave-scan + global cursor; also dis ----------------
// Segment order across nodes is arbitrary (one atomicAdd per wave); each dst's
// slots are contiguous, which is all the aggregation needs.
__global__ __launch_bounds__(256) void offsets_kernel(const int* __restrict__ deg,
                                                      float* __restrict__ dis,
                                                      int* __restrict__ offset,
                                                      int* __restrict__ cur,
                                                      int* __restrict__ cursor) {
    int n = blockIdx.x * 256 + threadIdx.x;
    int lane = threadIdx.x & 63;
    int d = (n < NN) ? deg[n] : 0;
    int inc = d;
#pragma unroll
    for (int m = 1; m < 64; m <<= 1) {
        int t = __shfl_up(inc, m, 64);
        if (lane >= m) inc += t;
    }
    int base = 0;
    if (lane == 63) base = atomicAdd(cursor, inc);  // lane63's inc == wave total
    base = __shfl(base, 63, 64);
    if (n < NN) {
        int off = base + inc - d;
        offset[n] = off;
        cur[n] = off;
        dis[n] = rsqrtf((float)d + 1.0f);
    }
}

// ---------------- CSR fill ----------------
__global__ __launch_bounds__(256) void fill_kernel(const int* __restrict__ src,
                                                   const int* __restrict__ dst,
                                                   int* __restrict__ cur,
                                                   int* __restrict__ csr_src) {
    int e = blockIdx.x * 256 + threadIdx.x;
    if (e >= NE) return;
    int s = src[e], d = dst[e];
    int p = atomicAdd(&cur[d], 1);
    csr_src[p] = s;
}

// ---------------- matmul 1: ys1 = dis * (x @ W1), [NN,128]@[128,64] ----------------
__global__ __launch_bounds__(256) void mm1_kernel(const float* __restrict__ x,
                                                  const float* __restrict__ W,
                                                  const float* __restrict__ dis,
                                                  float* __restrict__ y) {
    __shared__ float Ws[128 * 64];
    __shared__ float xs[4][4][132];
    int t = threadIdx.x;
    for (int i = t; i < 128 * 64; i += 256) Ws[i] = W[i];
    int wave = t >> 6, lane = t & 63;
    int nsub = lane >> 4;
    int o4 = (lane & 15) * 4;
    int base = blockIdx.x * 16 + wave * 4;  // 6250 blocks * 16 = 100000 exact
#pragma unroll
    for (int r = 0; r < 4; ++r) {
        xs[wave][r][lane] = x[(size_t)(base + r) * 128 + lane];
        xs[wave][r][lane + 64] = x[(size_t)(base + r) * 128 + 64 + lane];
    }
    __syncthreads();
    float4 acc = {0.f, 0.f, 0.f, 0.f};
#pragma unroll 16
    for (int k = 0; k < 128; ++k) {
        float a = xs[wave][nsub][k];
        const float4 w = *(const float4*)&Ws[k * 64 + o4];
        acc.x = fmaf(a, w.x, acc.x);
        acc.y = fmaf(a, w.y, acc.y);
        acc.z = fmaf(a, w.z, acc.z);
        acc.w = fmaf(a, w.w, acc.w);
    }
    float sc = dis[base + nsub];
    acc.x *= sc; acc.y *= sc; acc.z *= sc; acc.w *= sc;
    *(float4*)&y[(size_t)(base + nsub) * 64 + o4] = acc;
}

// ---------------- matmul 2: ys2 = dis * (h @ W2), [NN,64]@[64,32] ----------------
__global__ __launch_bounds__(256) void mm2_kernel(const float* __restrict__ h,
                                                  const float* __restrict__ W,
                                                  const float* __restrict__ dis,
                                                  float* __restrict__ y) {
    __shared__ float Ws[64 * 32];
    __shared__ float hs[4][8][68];
    int t = threadIdx.x;
    for (int i = t; i < 64 * 32; i += 256) Ws[i] = W[i];
    int wave = t >> 6, lane = t & 63;
    int nsub = lane >> 3;
    int o4 = (lane & 7) * 4;
    int base = blockIdx.x * 32 + wave * 8;  // 3125 blocks * 32 = 100000 exact
#pragma unroll
    for (int r = 0; r < 8; ++r)
        hs[wave][r][lane] = h[(size_t)(base + r) * 64 + lane];
    __syncthreads();
    float4 acc = {0.f, 0.f, 0.f, 0.f};
#pragma unroll 16
    for (int k = 0; k < 64; ++k) {
        float a = hs[wave][nsub][k];
        const float4 w = *(const float4*)&Ws[k * 32 + o4];
        acc.x = fmaf(a, w.x, acc.x);
        acc.y = fmaf(a, w.y, acc.y);
        acc.z = fmaf(a, w.z, acc.z);
        acc.w = fmaf(a, w.w, acc.w);
    }
    float sc = dis[base + nsub];
    acc.x *= sc; acc.y *= sc; acc.z *= sc; acc.w *= sc;
    *(float4*)&y[(size_t)(base + nsub) * 32 + o4] = acc;
}

// ---------------- fused gather-aggregate, dim 64: h = relu(dis*(ys[d]+sum)+b) ----------------
// 16 lanes per node, each lane owns a float4 slice. No atomics.
__global__ __launch_bounds__(256) void agg64_kernel(const float* __restrict__ ys,
                                                    const float* __restrict__ dis,
                                                    const int* __restrict__ offset,
                                                    const int* __restrict__ deg,
                                                    const int* __restrict__ csr_src,
                                                    const float* __restrict__ b,
                                                    float* __restrict__ h) {
    int tid = blockIdx.x * 256 + threadIdx.x;
    int nd = tid >> 4, c4 = (tid & 15) * 4;
    if (nd >= NN) return;
    int start = offset[nd], dg = deg[nd];
    float4 acc = *(const float4*)&ys[(size_t)nd * 64 + c4];  // self-loop term
    for (int i = 0; i < dg; ++i) {
        int s = csr_src[start + i];
        const float4 v = *(const float4*)&ys[(size_t)s * 64 + c4];
        acc.x += v.x; acc.y += v.y; acc.z += v.z; acc.w += v.w;
    }
    float ds = dis[nd];
    const float4 bv = *(const float4*)&b[c4];
    acc.x = fmaxf(fmaf(ds, acc.x, bv.x), 0.f);
    acc.y = fmaxf(fmaf(ds, acc.y, bv.y), 0.f);
    acc.z = fmaxf(fmaf(ds, acc.z, bv.z), 0.f);
    acc.w = fmaxf(fmaf(ds, acc.w, bv.w), 0.f);
    *(float4*)&h[(size_t)nd * 64 + c4] = acc;
}

// ---------------- fused gather-aggregate, dim 32 (no relu) ----------------
__global__ __launch_bounds__(256) void agg32_kernel(const float* __restrict__ ys,
                                                    const float* __restrict__ dis,
                                                    const int* __restrict__ offset,
                                                    const int* __restrict__ deg,
                                                    const int* __restrict__ csr_src,
                                                    const float* __restrict__ b,
                                                    float* __restrict__ z) {
    int tid = blockIdx.x * 256 + threadIdx.x;
    int nd = tid >> 3, c4 = (tid & 7) * 4;
    if (nd >= NN) return;
    int start = offset[nd], dg = deg[nd];
    float4 acc = *(const float4*)&ys[(size_t)nd * 32 + c4];
    for (int i = 0; i < dg; ++i) {
        int s = csr_src[start + i];
        const float4 v = *(const float4*)&ys[(size_t)s * 32 + c4];
        acc.x += v.x; acc.y += v.y; acc.z += v.z; acc.w += v.w;
    }
    float ds = dis[nd];
    const float4 bv = *(const float4*)&b[c4];
    acc.x = fmaf(ds, acc.x, bv.x);
    acc.y = fmaf(ds, acc.y, bv.y);
    acc.z = fmaf(ds, acc.z, bv.z);
    acc.w = fmaf(ds, acc.w, bv.w);
    *(float4*)&z[(size_t)nd * 32 + c4] = acc;
}

// ---------------- decode: sigmoid(dot(z[src], z[dst])) ----------------
__global__ __launch_bounds__(256) void decode_kernel(const float* __restrict__ z,
                                                     const int* __restrict__ src,
                                                     const int* __restrict__ dst,
                                                     float* __restrict__ out) {
    int tid = blockIdx.x * 256 + threadIdx.x;
    int e = tid >> 5, k = tid & 31;
    if (e >= NE) return;
    int s = src[e], d = dst[e];
    float a = z[(size_t)s * 32 + k] * z[(size_t)d * 32 + k];
#pragma unroll
    for (int m = 16; m >= 1; m >>= 1) a += __shfl_xor(a, m, 32);
    if (k == 0) out[e] = 1.0f / (1.0f + expf(-a));
}

// ---------------- launcher ----------------
extern "C" void kernel_launch(void* const* d_in, const int* in_sizes, int n_in,
                              void* d_out, int out_size, void* d_ws, size_t ws_size,
                              hipStream_t stream) {
    const float* emb = (const float*)d_in[0];
    const float* W1  = (const float*)d_in[1];
    const float* b1  = (const float*)d_in[2];
    const float* W2  = (const float*)d_in[3];
    const float* b2  = (const float*)d_in[4];
    const int*   ei  = (const int*)d_in[5];
    const int* src = ei;
    const int* dst = ei + NE;
    float* out = (float*)d_out;

    // workspace layout (all 4-byte elements)
    char* w = (char*)d_ws;
    int*   deg     = (int*)w;                      w += NPAD * 4;
    float* dis     = (float*)w;                    w += NPAD * 4;
    int*   offset  = (int*)w;                      w += NPAD * 4;
    int*   cur     = (int*)w;                      w += NPAD * 4;
    int*   cursor  = (int*)w;                      w += 256;
    int*   csr_src = (int*)w;                      w += (size_t)NE * 4;
    float* ys1     = (float*)w;                    w += (size_t)NN * 64 * 4;
    float* h       = (float*)w;                    // NN*64 floats
    float* ys2 = ys1;                          // overlays dead ys1
    float* z   = ys1 + (size_t)NN * 32;        // overlays dead ys1 (2nd half)

    hipMemsetAsync(deg, 0, NN * sizeof(int), stream);
    hipMemsetAsync(cursor, 0, sizeof(int), stream);

    // CSR build
    deg_kernel<<<(NE + 255) / 256, 256, 0, stream>>>(dst, deg);
    offsets_kernel<<<(NN + 255) / 256, 256, 0, stream>>>(deg, dis, offset, cur, cursor);
    fill_kernel<<<(NE + 255) / 256, 256, 0, stream>>>(src, dst, cur, csr_src);

    // layer 1
    mm1_kernel<<<NN / 16, 256, 0, stream>>>(emb, W1, dis, ys1);
    agg64_kernel<<<(NN * 16) / 256, 256, 0, stream>>>(ys1, dis, offset, deg, csr_src, b1, h);

    // layer 2 (ys2/z overlay dead ys1)
    mm2_kernel<<<NN / 32, 256, 0, stream>>>(h, W2, dis, ys2);
    agg32_kernel<<<(NN * 8) / 256, 256, 0, stream>>>(ys2, dis, offset, deg, csr_src, b2, z);

    // decode
    decode_kernel<<<((size_t)NE * 32) / 256, 256, 0, stream>>>(z, src, dst, out);
}

// Round 3
// 690.745 us; speedup vs baseline: 6.6640x; 1.4699x over previous
//
#include <hip/hip_runtime.h>
#include <math.h>

#define NN 100000
#define NE 3200000
#define NPAD 100096
#define NB 196        // buckets: dst>>9, 512 nodes each (195 max for dst<100000)
#define BN 512        // nodes per bucket
#define EPB 8192      // edges per block in hist/scatter passes
#define NBLK 391      // ceil(NE/EPB)

// ---------------- pass A: per-block bucket histogram ----------------
__global__ __launch_bounds__(256) void hist_kernel(const int* __restrict__ dst,
                                                   int* __restrict__ blkhist) {
    __shared__ int cnt[NB];
    int t = threadIdx.x;
    for (int i = t; i < NB; i += 256) cnt[i] = 0;
    __syncthreads();
    int e0 = blockIdx.x * EPB;
    int e1 = min(e0 + EPB, NE);
    for (int e = e0 + t; e < e1; e += 256) atomicAdd(&cnt[dst[e] >> 9], 1);
    __syncthreads();
    for (int i = t; i < NB; i += 256) blkhist[blockIdx.x * NB + i] = cnt[i];
}

// ---------------- pass B: turn histograms into per-(block,bucket) cursors ----------------
__global__ __launch_bounds__(256) void scan_kernel(int* __restrict__ blkhist,
                                                   int* __restrict__ bucket_base) {
    __shared__ int tot[NB];
    __shared__ int base[NB + 1];
    int j = threadIdx.x;
    if (j < NB) {
        int s = 0;
        for (int b = 0; b < NBLK; ++b) s += blkhist[b * NB + j];
        tot[j] = s;
    }
    __syncthreads();
    if (j == 0) {
        int r = 0;
        for (int i = 0; i < NB; ++i) { base[i] = r; r += tot[i]; }
        base[NB] = r;
    }
    __syncthreads();
    if (j < NB) {
        int r = base[j];
        for (int b = 0; b < NBLK; ++b) {
            int v = blkhist[b * NB + j];
            blkhist[b * NB + j] = r;   // becomes this block's write cursor for bucket j
            r += v;
        }
    }
    if (j <= NB) bucket_base[j] = base[j];
}

// ---------------- pass C: scatter (src,dst) pairs into bucket-grouped runs ----------------
__global__ __launch_bounds__(256) void scatter_kernel(const int* __restrict__ src,
                                                      const int* __restrict__ dst,
                                                      const int* __restrict__ blkhist,
                                                      int2* __restrict__ staged) {
    __shared__ int cur[NB];
    int t = threadIdx.x;
    for (int i = t; i < NB; i += 256) cur[i] = blkhist[blockIdx.x * NB + i];
    __syncthreads();
    int e0 = blockIdx.x * EPB;
    int e1 = min(e0 + EPB, NE);
    for (int e = e0 + t; e < e1; e += 256) {
        int s = src[e], d = dst[e];
        int p = atomicAdd(&cur[d >> 9], 1);     // LDS atomic
        staged[p] = make_int2(s, d);
    }
}

// ---------------- pass D: per-bucket fine counting sort + offsets + dis ----------------
__global__ __launch_bounds__(256) void fine_kernel(const int2* __restrict__ staged,
                                                   const int* __restrict__ bucket_base,
                                                   int* __restrict__ offset,
                                                   float* __restrict__ dis,
                                                   int* __restrict__ csr_src) {
    __shared__ int hist[BN];
    __shared__ int offs[BN];
    __shared__ int cur[BN];
    int t = threadIdx.x, j = blockIdx.x;
    int bb = bucket_base[j], be = bucket_base[j + 1];
    for (int i = t; i < BN; i += 256) hist[i] = 0;
    __syncthreads();
    for (int e = bb + t; e < be; e += 256) atomicAdd(&hist[staged[e].y & (BN - 1)], 1);
    __syncthreads();
    if (t < 64) {  // wave0: exclusive scan of 512 counts
        int v[8]; int s = 0;
#pragma unroll
        for (int k = 0; k < 8; ++k) { v[k] = hist[t * 8 + k]; s += v[k]; }
        int inc = s;
#pragma unroll
        for (int m = 1; m < 64; m <<= 1) {
            int u = __shfl_up(inc, m, 64);
            if (t >= m) inc += u;
        }
        int run = inc - s;
#pragma unroll
        for (int k = 0; k < 8; ++k) { offs[t * 8 + k] = run; run += v[k]; }
    }
    __syncthreads();
    for (int l = t; l < BN; l += 256) {
        cur[l] = offs[l];
        int n = j * BN + l;
        if (n < NN) {
            offset[n] = bb + offs[l];
            dis[n] = rsqrtf((float)hist[l] + 1.0f);
        }
    }
    if (j == NB - 1 && t == 0) offset[NN] = NE;
    __syncthreads();
    for (int e = bb + t; e < be; e += 256) {
        int2 p = staged[e];
        int r = atomicAdd(&cur[p.y & (BN - 1)], 1);  // LDS atomic
        csr_src[bb + r] = p.x;                       // write within 65KB L2 window
    }
}

// ---------------- matmul 1: ys1 = dis * (x @ W1), [NN,128]@[128,64] ----------------
__global__ __launch_bounds__(256) void mm1_kernel(const float* __restrict__ x,
                                                  const float* __restrict__ W,
                                                  const float* __restrict__ dis,
                                                  float* __restrict__ y) {
    __shared__ float Ws[128 * 64];
    __shared__ float xs[4][4][132];
    int t = threadIdx.x;
    for (int i = t; i < 128 * 64; i += 256) Ws[i] = W[i];
    int wave = t >> 6, lane = t & 63;
    int nsub = lane >> 4;
    int o4 = (lane & 15) * 4;
    int base = blockIdx.x * 16 + wave * 4;
#pragma unroll
    for (int r = 0; r < 4; ++r) {
        xs[wave][r][lane] = x[(size_t)(base + r) * 128 + lane];
        xs[wave][r][lane + 64] = x[(size_t)(base + r) * 128 + 64 + lane];
    }
    __syncthreads();
    float4 acc = {0.f, 0.f, 0.f, 0.f};
#pragma unroll 16
    for (int k = 0; k < 128; ++k) {
        float a = xs[wave][nsub][k];
        const float4 w = *(const float4*)&Ws[k * 64 + o4];
        acc.x = fmaf(a, w.x, acc.x);
        acc.y = fmaf(a, w.y, acc.y);
        acc.z = fmaf(a, w.z, acc.z);
        acc.w = fmaf(a, w.w, acc.w);
    }
    float sc = dis[base + nsub];
    acc.x *= sc; acc.y *= sc; acc.z *= sc; acc.w *= sc;
    *(float4*)&y[(size_t)(base + nsub) * 64 + o4] = acc;
}

// ---------------- matmul 2: ys2 = dis * (h @ W2), [NN,64]@[64,32] ----------------
__global__ __launch_bounds__(256) void mm2_kernel(const float* __restrict__ h,
                                                  const float* __restrict__ W,
                                                  const float* __restrict__ dis,
                                                  float* __restrict__ y) {
    __shared__ float Ws[64 * 32];
    __shared__ float hs[4][8][68];
    int t = threadIdx.x;
    for (int i = t; i < 64 * 32; i += 256) Ws[i] = W[i];
    int wave = t >> 6, lane = t & 63;
    int nsub = lane >> 3;
    int o4 = (lane & 7) * 4;
    int base = blockIdx.x * 32 + wave * 8;
#pragma unroll
    for (int r = 0; r < 8; ++r)
        hs[wave][r][lane] = h[(size_t)(base + r) * 64 + lane];
    __syncthreads();
    float4 acc = {0.f, 0.f, 0.f, 0.f};
#pragma unroll 16
    for (int k = 0; k < 64; ++k) {
        float a = hs[wave][nsub][k];
        const float4 w = *(const float4*)&Ws[k * 32 + o4];
        acc.x = fmaf(a, w.x, acc.x);
        acc.y = fmaf(a, w.y, acc.y);
        acc.z = fmaf(a, w.z, acc.z);
        acc.w = fmaf(a, w.w, acc.w);
    }
    float sc = dis[base + nsub];
    acc.x *= sc; acc.y *= sc; acc.z *= sc; acc.w *= sc;
    *(float4*)&y[(size_t)(base + nsub) * 32 + o4] = acc;
}

// ---------------- fused gather-aggregate, dim 64: h = relu(dis*(ys[d]+sum)+b) ----------------
__global__ __launch_bounds__(256) void agg64_kernel(const float* __restrict__ ys,
                                                    const float* __restrict__ dis,
                                                    const int* __restrict__ offset,
                                                    const int* __restrict__ csr_src,
                                                    const float* __restrict__ b,
                                                    float* __restrict__ h) {
    int tid = blockIdx.x * 256 + threadIdx.x;
    int nd = tid >> 4, c4 = (tid & 15) * 4;
    if (nd >= NN) return;
    int start = offset[nd], end = offset[nd + 1];
    float4 acc = *(const float4*)&ys[(size_t)nd * 64 + c4];  // self-loop term
    for (int i = start; i < end; ++i) {
        int s = csr_src[i];
        const float4 v = *(const float4*)&ys[(size_t)s * 64 + c4];
        acc.x += v.x; acc.y += v.y; acc.z += v.z; acc.w += v.w;
    }
    float ds = dis[nd];
    const float4 bv = *(const float4*)&b[c4];
    acc.x = fmaxf(fmaf(ds, acc.x, bv.x), 0.f);
    acc.y = fmaxf(fmaf(ds, acc.y, bv.y), 0.f);
    acc.z = fmaxf(fmaf(ds, acc.z, bv.z), 0.f);
    acc.w = fmaxf(fmaf(ds, acc.w, bv.w), 0.f);
    *(float4*)&h[(size_t)nd * 64 + c4] = acc;
}

// ---------------- fused gather-aggregate, dim 32 (no relu) ----------------
__global__ __launch_bounds__(256) void agg32_kernel(const float* __restrict__ ys,
                                                    const float* __restrict__ dis,
                                                    const int* __restrict__ offset,
                                                    const int* __restrict__ csr_src,
                                                    const float* __restrict__ b,
                                                    float* __restrict__ z) {
    int tid = blockIdx.x * 256 + threadIdx.x;
    int nd = tid >> 3, c4 = (tid & 7) * 4;
    if (nd >= NN) return;
    int start = offset[nd], end = offset[nd + 1];
    float4 acc = *(const float4*)&ys[(size_t)nd * 32 + c4];
    for (int i = start; i < end; ++i) {
        int s = csr_src[i];
        const float4 v = *(const float4*)&ys[(size_t)s * 32 + c4];
        acc.x += v.x; acc.y += v.y; acc.z += v.z; acc.w += v.w;
    }
    float ds = dis[nd];
    const float4 bv = *(const float4*)&b[c4];
    acc.x = fmaf(ds, acc.x, bv.x);
    acc.y = fmaf(ds, acc.y, bv.y);
    acc.z = fmaf(ds, acc.z, bv.z);
    acc.w = fmaf(ds, acc.w, bv.w);
    *(float4*)&z[(size_t)nd * 32 + c4] = acc;
}

// ---------------- decode: sigmoid(dot(z[src], z[dst])), 8 lanes/edge ----------------
__global__ __launch_bounds__(256) void decode_kernel(const float4* __restrict__ z4,
                                                     const int* __restrict__ src,
                                                     const int* __restrict__ dst,
                                                     float* __restrict__ out) {
    int tid = blockIdx.x * 256 + threadIdx.x;
    int e = tid >> 3, k = tid & 7;
    if (e >= NE) return;
    int s = src[e], d = dst[e];
    const float4 a = z4[(size_t)s * 8 + k];
    const float4 b = z4[(size_t)d * 8 + k];
    float acc = a.x * b.x + a.y * b.y + a.z * b.z + a.w * b.w;
#pragma unroll
    for (int m = 4; m >= 1; m >>= 1) acc += __shfl_xor(acc, m, 8);
    if (k == 0) out[e] = 1.0f / (1.0f + expf(-acc));
}

// ---------------- launcher ----------------
extern "C" void kernel_launch(void* const* d_in, const int* in_sizes, int n_in,
                              void* d_out, int out_size, void* d_ws, size_t ws_size,
                              hipStream_t stream) {
    const float* emb = (const float*)d_in[0];
    const float* W1  = (const float*)d_in[1];
    const float* b1  = (const float*)d_in[2];
    const float* W2  = (const float*)d_in[3];
    const float* b2  = (const float*)d_in[4];
    const int*   ei  = (const int*)d_in[5];
    const int* src = ei;
    const int* dst = ei + NE;
    float* out = (float*)d_out;

    // workspace layout (byte offsets all 16B-aligned)
    char* w = (char*)d_ws;
    int*   offset      = (int*)w;          w += (size_t)NPAD * 4;
    float* dis         = (float*)w;        w += (size_t)NPAD * 4;
    int*   bucket_base = (int*)w;          w += 1024;
    int*   blkhist     = (int*)w;          w += (size_t)NBLK * NB * 4 + 2048;  // ~307KB
    int*   csr_src     = (int*)w;          w += (size_t)NE * 4;                // 12.8MB
    int2*  staged      = (int2*)w;         w += (size_t)NE * 8;                // 25.6MB
    float* h           = (float*)w;                                            // 25.6MB
    float* ys1 = (float*)staged;           // overlays staged (dead after fine_kernel)
    float* ys2 = ys1;                      // overlays dead ys1 (first half)
    float* z   = ys1 + (size_t)NN * 32;    // second half of the ys1 region

    // CSR build — no global atomics, no memsets
    hist_kernel<<<NBLK, 256, 0, stream>>>(dst, blkhist);
    scan_kernel<<<1, 256, 0, stream>>>(blkhist, bucket_base);
    scatter_kernel<<<NBLK, 256, 0, stream>>>(src, dst, blkhist, staged);
    fine_kernel<<<NB, 256, 0, stream>>>(staged, bucket_base, offset, dis, csr_src);

    // layer 1
    mm1_kernel<<<NN / 16, 256, 0, stream>>>(emb, W1, dis, ys1);
    agg64_kernel<<<(NN * 16) / 256, 256, 0, stream>>>(ys1, dis, offset, csr_src, b1, h);

    // layer 2
    mm2_kernel<<<NN / 32, 256, 0, stream>>>(h, W2, dis, ys2);
    agg32_kernel<<<(NN * 8) / 256, 256, 0, stream>>>(ys2, dis, offset, csr_src, b2, z);

    // decode
    decode_kernel<<<(NE * 8) / 256, 256, 0, stream>>>((const float4*)z, src, dst, out);
}

// Round 4
// 401.008 us; speedup vs baseline: 11.4788x; 1.7225x over previous
//
#include <hip/hip_runtime.h>
#include <hip/hip_bf16.h>
#include <math.h>

#define NN 100000
#define NE 3200000
#define NPAD 100096
#define NB 196        // buckets: dst>>9, 512 nodes each
#define BN 512        // nodes per bucket
#define EPB 8192      // edges per block in hist/scatter passes
#define NBLK 391      // ceil(NE/EPB)

// ---------------- bf16 helpers (storage bf16, math fp32) ----------------
__device__ __forceinline__ unsigned short bf16_of(float x) {
    __hip_bfloat16 h = __float2bfloat16(x);  // RNE
    return *(unsigned short*)&h;
}
__device__ __forceinline__ unsigned pack2(float a, float b) {
    return (unsigned)bf16_of(a) | ((unsigned)bf16_of(b) << 16);
}
__device__ __forceinline__ float lo_f(unsigned u) { return __uint_as_float(u << 16); }
__device__ __forceinline__ float hi_f(unsigned u) { return __uint_as_float(u & 0xffff0000u); }
// accumulate 8 bf16 (one uint4) into acc[8]
__device__ __forceinline__ void acc8(float* a, uint4 r) {
    a[0] += lo_f(r.x); a[1] += hi_f(r.x);
    a[2] += lo_f(r.y); a[3] += hi_f(r.y);
    a[4] += lo_f(r.z); a[5] += hi_f(r.z);
    a[6] += lo_f(r.w); a[7] += hi_f(r.w);
}

// ---------------- pass A: per-block bucket histogram (bucket-major out) ----------------
__global__ __launch_bounds__(256) void hist_kernel(const int* __restrict__ dst,
                                                   int* __restrict__ blkhist) {
    __shared__ int cnt[NB];
    int t = threadIdx.x;
    for (int i = t; i < NB; i += 256) cnt[i] = 0;
    __syncthreads();
    int e0 = blockIdx.x * EPB;
    int e1 = min(e0 + EPB, NE);
    for (int e = e0 + t; e < e1; e += 256) atomicAdd(&cnt[dst[e] >> 9], 1);
    __syncthreads();
    for (int i = t; i < NB; i += 256) blkhist[i * NBLK + blockIdx.x] = cnt[i];
}

// ---------------- pass B1: per-bucket exclusive scan along blocks ----------------
__global__ __launch_bounds__(64) void scanA_kernel(int* __restrict__ blkhist,
                                                   int* __restrict__ totals) {
    int j = blockIdx.x, lane = threadIdx.x;
    int base = j * NBLK;
    int carry = 0;
    for (int c = 0; c < NBLK; c += 64) {
        int b = c + lane;
        int v = (b < NBLK) ? blkhist[base + b] : 0;
        int inc = v;
#pragma unroll
        for (int m = 1; m < 64; m <<= 1) {
            int u = __shfl_up(inc, m, 64);
            if (lane >= m) inc += u;
        }
        if (b < NBLK) blkhist[base + b] = carry + inc - v;
        carry += __shfl(inc, 63, 64);
    }
    if (lane == 0) totals[j] = carry;
}

// ---------------- pass B2: bucket bases ----------------
__global__ __launch_bounds__(256) void scanB_kernel(const int* __restrict__ totals,
                                                    int* __restrict__ bucket_base) {
    __shared__ int sm[NB];
    int t = threadIdx.x;
    if (t < NB) sm[t] = totals[t];
    __syncthreads();
    if (t == 0) {
        int r = 0;
        for (int i = 0; i < NB; ++i) { bucket_base[i] = r; r += sm[i]; }
        bucket_base[NB] = r;
    }
}

// ---------------- pass C: scatter packed (src<<9 | dst&511) into bucket runs ----------------
__global__ __launch_bounds__(256) void scatter_kernel(const int* __restrict__ src,
                                                      const int* __restrict__ dst,
                                                      const int* __restrict__ blkhist,
                                                      const int* __restrict__ bucket_base,
                                                      int* __restrict__ staged) {
    __shared__ int cur[NB];
    int t = threadIdx.x;
    for (int i = t; i < NB; i += 256)
        cur[i] = bucket_base[i] + blkhist[i * NBLK + blockIdx.x];
    __syncthreads();
    int e0 = blockIdx.x * EPB;
    int e1 = min(e0 + EPB, NE);
    for (int e = e0 + t; e < e1; e += 256) {
        int s = src[e], d = dst[e];
        int p = atomicAdd(&cur[d >> 9], 1);        // LDS atomic
        staged[p] = (s << 9) | (d & (BN - 1));
    }
}

// ---------------- pass D: per-bucket fine counting sort + offsets + dis ----------------
__global__ __launch_bounds__(256) void fine_kernel(const int* __restrict__ staged,
                                                   const int* __restrict__ bucket_base,
                                                   int* __restrict__ offset,
                                                   float* __restrict__ dis,
                                                   int* __restrict__ csr_src) {
    __shared__ int hist[BN];
    __shared__ int offs[BN];
    __shared__ int cur[BN];
    int t = threadIdx.x, j = blockIdx.x;
    int bb = bucket_base[j], be = bucket_base[j + 1];
    for (int i = t; i < BN; i += 256) hist[i] = 0;
    __syncthreads();
    for (int e = bb + t; e < be; e += 256) atomicAdd(&hist[staged[e] & (BN - 1)], 1);
    __syncthreads();
    if (t < 64) {  // wave0: exclusive scan of 512 counts
        int v[8]; int s = 0;
#pragma unroll
        for (int k = 0; k < 8; ++k) { v[k] = hist[t * 8 + k]; s += v[k]; }
        int inc = s;
#pragma unroll
        for (int m = 1; m < 64; m <<= 1) {
            int u = __shfl_up(inc, m, 64);
            if (t >= m) inc += u;
        }
        int run = inc - s;
#pragma unroll
        for (int k = 0; k < 8; ++k) { offs[t * 8 + k] = run; run += v[k]; }
    }
    __syncthreads();
    for (int l = t; l < BN; l += 256) {
        cur[l] = offs[l];
        int n = j * BN + l;
        if (n < NN) {
            offset[n] = bb + offs[l];
            dis[n] = rsqrtf((float)hist[l] + 1.0f);
        }
    }
    if (j == NB - 1 && t == 0) offset[NN] = NE;
    __syncthreads();
    for (int e = bb + t; e < be; e += 256) {
        int p = staged[e];
        int r = atomicAdd(&cur[p & (BN - 1)], 1);  // LDS atomic
        csr_src[bb + r] = p >> 9;
    }
}

// ---------------- matmul 1: ys1 = bf16(dis * (x @ W1)) ----------------
__global__ __launch_bounds__(256) void mm1_kernel(const float* __restrict__ x,
                                                  const float* __restrict__ W,
                                                  const float* __restrict__ dis,
                                                  unsigned short* __restrict__ y) {
    __shared__ float Ws[128 * 64];
    __shared__ float xs[4][4][132];
    int t = threadIdx.x;
    for (int i = t; i < 128 * 64; i += 256) Ws[i] = W[i];
    int wave = t >> 6, lane = t & 63;
    int nsub = lane >> 4;
    int o4 = (lane & 15) * 4;
    int base = blockIdx.x * 16 + wave * 4;
#pragma unroll
    for (int r = 0; r < 4; ++r) {
        xs[wave][r][lane] = x[(size_t)(base + r) * 128 + lane];
        xs[wave][r][lane + 64] = x[(size_t)(base + r) * 128 + 64 + lane];
    }
    __syncthreads();
    float4 acc = {0.f, 0.f, 0.f, 0.f};
#pragma unroll 16
    for (int k = 0; k < 128; ++k) {
        float a = xs[wave][nsub][k];
        const float4 w = *(const float4*)&Ws[k * 64 + o4];
        acc.x = fmaf(a, w.x, acc.x);
        acc.y = fmaf(a, w.y, acc.y);
        acc.z = fmaf(a, w.z, acc.z);
        acc.w = fmaf(a, w.w, acc.w);
    }
    float sc = dis[base + nsub];
    ushort4 o;
    o.x = bf16_of(acc.x * sc); o.y = bf16_of(acc.y * sc);
    o.z = bf16_of(acc.z * sc); o.w = bf16_of(acc.w * sc);
    *(ushort4*)&y[(size_t)(base + nsub) * 64 + o4] = o;
}

// ---------------- matmul 2: ys2 = bf16(dis * (h @ W2)), h fp32 ----------------
__global__ __launch_bounds__(256) void mm2_kernel(const float* __restrict__ h,
                                                  const float* __restrict__ W,
                                                  const float* __restrict__ dis,
                                                  unsigned short* __restrict__ y) {
    __shared__ float Ws[64 * 32];
    __shared__ float hs[4][8][68];
    int t = threadIdx.x;
    for (int i = t; i < 64 * 32; i += 256) Ws[i] = W[i];
    int wave = t >> 6, lane = t & 63;
    int nsub = lane >> 3;
    int o4 = (lane & 7) * 4;
    int base = blockIdx.x * 32 + wave * 8;
#pragma unroll
    for (int r = 0; r < 8; ++r)
        hs[wave][r][lane] = h[(size_t)(base + r) * 64 + lane];
    __syncthreads();
    float4 acc = {0.f, 0.f, 0.f, 0.f};
#pragma unroll 16
    for (int k = 0; k < 64; ++k) {
        float a = hs[wave][nsub][k];
        const float4 w = *(const float4*)&Ws[k * 32 + o4];
        acc.x = fmaf(a, w.x, acc.x);
        acc.y = fmaf(a, w.y, acc.y);
        acc.z = fmaf(a, w.z, acc.z);
        acc.w = fmaf(a, w.w, acc.w);
    }
    float sc = dis[base + nsub];
    ushort4 o;
    o.x = bf16_of(acc.x * sc); o.y = bf16_of(acc.y * sc);
    o.z = bf16_of(acc.z * sc); o.w = bf16_of(acc.w * sc);
    *(ushort4*)&y[(size_t)(base + nsub) * 32 + o4] = o;
}

// ---------------- fused gather-aggregate, dim 64 bf16: h = relu(dis*(self+sum)+b) ----------
// 8 lanes per node, each lane owns 8 feats (16B bf16 gather). x4 unrolled edge loop.
__global__ __launch_bounds__(256) void agg64_kernel(const uint4* __restrict__ ys4,
                                                    const float* __restrict__ dis,
                                                    const int* __restrict__ offset,
                                                    const int* __restrict__ csr_src,
                                                    const float* __restrict__ b,
                                                    float* __restrict__ h) {
    int tid = blockIdx.x * 256 + threadIdx.x;
    int nd = tid >> 3, c = tid & 7;
    if (nd >= NN) return;
    int start = offset[nd], end = offset[nd + 1];
    float acc[8] = {0, 0, 0, 0, 0, 0, 0, 0};
    acc8(acc, ys4[(size_t)nd * 8 + c]);  // self-loop term
    int i = start;
    int n4 = start + ((end - start) & ~3);
    for (; i < n4; i += 4) {
        int s0 = csr_src[i], s1 = csr_src[i + 1], s2 = csr_src[i + 2], s3 = csr_src[i + 3];
        uint4 r0 = ys4[(size_t)s0 * 8 + c];
        uint4 r1 = ys4[(size_t)s1 * 8 + c];
        uint4 r2 = ys4[(size_t)s2 * 8 + c];
        uint4 r3 = ys4[(size_t)s3 * 8 + c];
        acc8(acc, r0); acc8(acc, r1); acc8(acc, r2); acc8(acc, r3);
    }
    for (; i < end; ++i) acc8(acc, ys4[(size_t)csr_src[i] * 8 + c]);
    float ds = dis[nd];
    const float4 bv0 = *(const float4*)&b[c * 8];
    const float4 bv1 = *(const float4*)&b[c * 8 + 4];
    float4 o0, o1;
    o0.x = fmaxf(fmaf(ds, acc[0], bv0.x), 0.f);
    o0.y = fmaxf(fmaf(ds, acc[1], bv0.y), 0.f);
    o0.z = fmaxf(fmaf(ds, acc[2], bv0.z), 0.f);
    o0.w = fmaxf(fmaf(ds, acc[3], bv0.w), 0.f);
    o1.x = fmaxf(fmaf(ds, acc[4], bv1.x), 0.f);
    o1.y = fmaxf(fmaf(ds, acc[5], bv1.y), 0.f);
    o1.z = fmaxf(fmaf(ds, acc[6], bv1.z), 0.f);
    o1.w = fmaxf(fmaf(ds, acc[7], bv1.w), 0.f);
    float* hp = &h[(size_t)nd * 64 + c * 8];
    *(float4*)hp = o0;
    *(float4*)(hp + 4) = o1;
}

// ---------------- fused gather-aggregate, dim 32 bf16 -> z bf16 ----------------
// 4 lanes per node, each lane owns 8 feats.
__global__ __launch_bounds__(256) void agg32_kernel(const uint4* __restrict__ ys4,
                                                    const float* __restrict__ dis,
                                                    const int* __restrict__ offset,
                                                    const int* __restrict__ csr_src,
                                                    const float* __restrict__ b,
                                                    uint4* __restrict__ z4) {
    int tid = blockIdx.x * 256 + threadIdx.x;
    int nd = tid >> 2, c = tid & 3;
    if (nd >= NN) return;
    int start = offset[nd], end = offset[nd + 1];
    float acc[8] = {0, 0, 0, 0, 0, 0, 0, 0};
    acc8(acc, ys4[(size_t)nd * 4 + c]);
    int i = start;
    int n4 = start + ((end - start) & ~3);
    for (; i < n4; i += 4) {
        int s0 = csr_src[i], s1 = csr_src[i + 1], s2 = csr_src[i + 2], s3 = csr_src[i + 3];
        uint4 r0 = ys4[(size_t)s0 * 4 + c];
        uint4 r1 = ys4[(size_t)s1 * 4 + c];
        uint4 r2 = ys4[(size_t)s2 * 4 + c];
        uint4 r3 = ys4[(size_t)s3 * 4 + c];
        acc8(acc, r0); acc8(acc, r1); acc8(acc, r2); acc8(acc, r3);
    }
    for (; i < end; ++i) acc8(acc, ys4[(size_t)csr_src[i] * 4 + c]);
    float ds = dis[nd];
    const float4 bv0 = *(const float4*)&b[c * 8];
    const float4 bv1 = *(const float4*)&b[c * 8 + 4];
    uint4 o;
    o.x = pack2(fmaf(ds, acc[0], bv0.x), fmaf(ds, acc[1], bv0.y));
    o.y = pack2(fmaf(ds, acc[2], bv0.z), fmaf(ds, acc[3], bv0.w));
    o.z = pack2(fmaf(ds, acc[4], bv1.x), fmaf(ds, acc[5], bv1.y));
    o.w = pack2(fmaf(ds, acc[6], bv1.z), fmaf(ds, acc[7], bv1.w));
    z4[(size_t)nd * 4 + c] = o;
}

// ---------------- decode: sigmoid(dot(z[src], z[dst])), 4 lanes/edge, bf16 z ---------
__global__ __launch_bounds__(256) void decode_kernel(const uint4* __restrict__ z4,
                                                     const int* __restrict__ src,
                                                     const int* __restrict__ dst,
                                                     float* __restrict__ out) {
    int tid = blockIdx.x * 256 + threadIdx.x;
    int e = tid >> 2, k = tid & 3;
    if (e >= NE) return;
    int s = src[e], d = dst[e];
    uint4 ra = z4[(size_t)s * 4 + k];
    uint4 rb = z4[(size_t)d * 4 + k];
    float acc;
    acc  = lo_f(ra.x) * lo_f(rb.x) + hi_f(ra.x) * hi_f(rb.x);
    acc += lo_f(ra.y) * lo_f(rb.y) + hi_f(ra.y) * hi_f(rb.y);
    acc += lo_f(ra.z) * lo_f(rb.z) + hi_f(ra.z) * hi_f(rb.z);
    acc += lo_f(ra.w) * lo_f(rb.w) + hi_f(ra.w) * hi_f(rb.w);
#pragma unroll
    for (int m = 2; m >= 1; m >>= 1) acc += __shfl_xor(acc, m, 4);
    if (k == 0) out[e] = 1.0f / (1.0f + expf(-acc));
}

// ---------------- launcher ----------------
extern "C" void kernel_launch(void* const* d_in, const int* in_sizes, int n_in,
                              void* d_out, int out_size, void* d_ws, size_t ws_size,
                              hipStream_t stream) {
    const float* emb = (const float*)d_in[0];
    const float* W1  = (const float*)d_in[1];
    const float* b1  = (const float*)d_in[2];
    const float* W2  = (const float*)d_in[3];
    const float* b2  = (const float*)d_in[4];
    const int*   ei  = (const int*)d_in[5];
    const int* src = ei;
    const int* dst = ei + NE;
    float* out = (float*)d_out;

    // workspace layout (byte offsets multiples of 256)
    char* w = (char*)d_ws;
    int*   offset      = (int*)w;           w += (size_t)NPAD * 4;       // 400384
    float* dis         = (float*)w;         w += (size_t)NPAD * 4;
    int*   bucket_base = (int*)w;           w += 1024;
    int*   totals      = (int*)w;           w += 1024;
    int*   blkhist     = (int*)w;           w += 307200;                 // NB*NBLK ints
    int*   csr_src     = (int*)w;           w += (size_t)NE * 4;         // 12.8MB
    int*   staged      = (int*)w;           w += (size_t)NE * 4;         // 12.8MB packed
    unsigned short* ysbuf = (unsigned short*)w; w += (size_t)NN * 64 * 2; // 12.8MB bf16
    float* h           = (float*)w;                                       // 25.6MB fp32
    unsigned short* ys1 = ysbuf;
    unsigned short* ys2 = ysbuf;                       // overlays dead ys1
    unsigned short* z   = ysbuf + (size_t)NN * 32;     // second half of ysbuf

    // CSR build — LDS atomics only
    hist_kernel<<<NBLK, 256, 0, stream>>>(dst, blkhist);
    scanA_kernel<<<NB, 64, 0, stream>>>(blkhist, totals);
    scanB_kernel<<<1, 256, 0, stream>>>(totals, bucket_base);
    scatter_kernel<<<NBLK, 256, 0, stream>>>(src, dst, blkhist, bucket_base, staged);
    fine_kernel<<<NB, 256, 0, stream>>>(staged, bucket_base, offset, dis, csr_src);

    // layer 1
    mm1_kernel<<<NN / 16, 256, 0, stream>>>(emb, W1, dis, ys1);
    agg64_kernel<<<(NN * 8) / 256, 256, 0, stream>>>((const uint4*)ys1, dis, offset, csr_src, b1, h);

    // layer 2
    mm2_kernel<<<NN / 32, 256, 0, stream>>>(h, W2, dis, ys2);
    agg32_kernel<<<(NN * 4 + 255) / 256, 256, 0, stream>>>((const uint4*)ys2, dis, offset, csr_src, b2, (uint4*)z);

    // decode
    decode_kernel<<<(NE * 4) / 256, 256, 0, stream>>>((const uint4*)z, src, dst, out);
}

// Round 5
// 398.254 us; speedup vs baseline: 11.5582x; 1.0069x over previous
//
#include <hip/hip_runtime.h>
#include <hip/hip_bf16.h>
#include <math.h>

#define NN 100000
#define NE 3200000
#define NPAD 100096
#define NB 196        // buckets: dst>>9, 512 nodes each
#define BN 512        // nodes per bucket
#define EPB 8192      // edges per block in hist/scatter passes
#define NBLK 391      // ceil(NE/EPB)

// ---------------- bf16 helpers (storage bf16, math fp32) ----------------
__device__ __forceinline__ unsigned short bf16_of(float x) {
    __hip_bfloat16 h = __float2bfloat16(x);  // RNE
    return *(unsigned short*)&h;
}
__device__ __forceinline__ unsigned pack2(float a, float b) {
    return (unsigned)bf16_of(a) | ((unsigned)bf16_of(b) << 16);
}
__device__ __forceinline__ float lo_f(unsigned u) { return __uint_as_float(u << 16); }
__device__ __forceinline__ float hi_f(unsigned u) { return __uint_as_float(u & 0xffff0000u); }
__device__ __forceinline__ void acc8(float* a, uint4 r) {
    a[0] += lo_f(r.x); a[1] += hi_f(r.x);
    a[2] += lo_f(r.y); a[3] += hi_f(r.y);
    a[4] += lo_f(r.z); a[5] += hi_f(r.z);
    a[6] += lo_f(r.w); a[7] += hi_f(r.w);
}

// ---------------- pass A: per-block bucket histogram (bucket-major out) ----------------
__global__ __launch_bounds__(256) void hist_kernel(const int* __restrict__ dst,
                                                   int* __restrict__ blkhist) {
    __shared__ int cnt[NB];
    int t = threadIdx.x;
    for (int i = t; i < NB; i += 256) cnt[i] = 0;
    __syncthreads();
    int e0 = blockIdx.x * EPB;
    int e1 = min(e0 + EPB, NE);
    for (int e = e0 + t; e < e1; e += 256) atomicAdd(&cnt[dst[e] >> 9], 1);
    __syncthreads();
    for (int i = t; i < NB; i += 256) blkhist[i * NBLK + blockIdx.x] = cnt[i];
}

// ---------------- pass B1: per-bucket exclusive scan along blocks ----------------
__global__ __launch_bounds__(64) void scanA_kernel(int* __restrict__ blkhist,
                                                   int* __restrict__ totals) {
    int j = blockIdx.x, lane = threadIdx.x;
    int base = j * NBLK;
    int carry = 0;
    for (int c = 0; c < NBLK; c += 64) {
        int b = c + lane;
        int v = (b < NBLK) ? blkhist[base + b] : 0;
        int inc = v;
#pragma unroll
        for (int m = 1; m < 64; m <<= 1) {
            int u = __shfl_up(inc, m, 64);
            if (lane >= m) inc += u;
        }
        if (b < NBLK) blkhist[base + b] = carry + inc - v;
        carry += __shfl(inc, 63, 64);
    }
    if (lane == 0) totals[j] = carry;
}

// ---------------- pass B2: bucket bases ----------------
__global__ __launch_bounds__(256) void scanB_kernel(const int* __restrict__ totals,
                                                    int* __restrict__ bucket_base) {
    __shared__ int sm[NB];
    int t = threadIdx.x;
    if (t < NB) sm[t] = totals[t];
    __syncthreads();
    if (t == 0) {
        int r = 0;
        for (int i = 0; i < NB; ++i) { bucket_base[i] = r; r += sm[i]; }
        bucket_base[NB] = r;
    }
}

// ---------------- pass C: LDS-staged scatter -> contiguous run writes ----------------
__global__ __launch_bounds__(256) void scatter_kernel(const int* __restrict__ src,
                                                      const int* __restrict__ dst,
                                                      const int* __restrict__ blkhist,
                                                      const int* __restrict__ bucket_base,
                                                      int* __restrict__ staged) {
    __shared__ int cnt[NB];
    __shared__ int lbase[NB + 1];
    __shared__ int gbase[NB];
    __shared__ int sbuf[EPB];   // 32KB
    int t = threadIdx.x;
    for (int i = t; i < NB; i += 256) cnt[i] = 0;
    __syncthreads();
    int e0 = blockIdx.x * EPB;
    int e1 = min(e0 + EPB, NE);
    int cn = e1 - e0;
    for (int e = e0 + t; e < e1; e += 256) atomicAdd(&cnt[dst[e] >> 9], 1);
    __syncthreads();
    if (t < 64) {  // exclusive scan of 196 counts, 4 per lane
        int v[4]; int s = 0;
#pragma unroll
        for (int k = 0; k < 4; ++k) { int idx = t * 4 + k; v[k] = (idx < NB) ? cnt[idx] : 0; s += v[k]; }
        int inc = s;
#pragma unroll
        for (int m = 1; m < 64; m <<= 1) {
            int u = __shfl_up(inc, m, 64);
            if (t >= m) inc += u;
        }
        int run = inc - s;
#pragma unroll
        for (int k = 0; k < 4; ++k) { int idx = t * 4 + k; if (idx < NB) lbase[idx] = run; run += v[k]; }
        if (t == 63) lbase[NB] = inc;  // == cn
    }
    __syncthreads();
    for (int i = t; i < NB; i += 256) {
        gbase[i] = bucket_base[i] + blkhist[i * NBLK + blockIdx.x];
        cnt[i] = lbase[i];            // rank cursors
    }
    __syncthreads();
    for (int e = e0 + t; e < e1; e += 256) {
        int s = src[e], d = dst[e];
        int r = atomicAdd(&cnt[d >> 9], 1);     // LDS atomic
        sbuf[r] = (s << 9) | (d & (BN - 1));
    }
    __syncthreads();
    for (int i = t; i < cn; i += 256) {         // contiguous run write-out
        int lo = 0, hi = NB - 1;
        while (lo < hi) { int mid = (lo + hi + 1) >> 1; if (lbase[mid] <= i) lo = mid; else hi = mid - 1; }
        staged[gbase[lo] + i - lbase[lo]] = sbuf[i];
    }
}

// ---------------- pass D: per-bucket fine counting sort + offsets + dis ----------------
__global__ __launch_bounds__(256) void fine_kernel(const int* __restrict__ staged,
                                                   const int* __restrict__ bucket_base,
                                                   int* __restrict__ offset,
                                                   float* __restrict__ dis,
                                                   int* __restrict__ csr_src) {
    __shared__ int hist[BN];
    __shared__ int offs[BN];
    __shared__ int cur[BN];
    int t = threadIdx.x, j = blockIdx.x;
    int bb = bucket_base[j], be = bucket_base[j + 1];
    for (int i = t; i < BN; i += 256) hist[i] = 0;
    __syncthreads();
    for (int e = bb + t; e < be; e += 256) atomicAdd(&hist[staged[e] & (BN - 1)], 1);
    __syncthreads();
    if (t < 64) {  // wave0: exclusive scan of 512 counts
        int v[8]; int s = 0;
#pragma unroll
        for (int k = 0; k < 8; ++k) { v[k] = hist[t * 8 + k]; s += v[k]; }
        int inc = s;
#pragma unroll
        for (int m = 1; m < 64; m <<= 1) {
            int u = __shfl_up(inc, m, 64);
            if (t >= m) inc += u;
        }
        int run = inc - s;
#pragma unroll
        for (int k = 0; k < 8; ++k) { offs[t * 8 + k] = run; run += v[k]; }
    }
    __syncthreads();
    for (int l = t; l < BN; l += 256) {
        cur[l] = offs[l];
        int n = j * BN + l;
        if (n < NN) {
            offset[n] = bb + offs[l];
            dis[n] = rsqrtf((float)hist[l] + 1.0f);
        }
    }
    if (j == NB - 1 && t == 0) offset[NN] = NE;
    __syncthreads();
    for (int e = bb + t; e < be; e += 256) {
        int p = staged[e];
        int r = atomicAdd(&cur[p & (BN - 1)], 1);  // LDS atomic
        csr_src[bb + r] = p >> 9;
    }
}

// ---------------- matmul 1: ys1 = bf16(dis * (x @ W1)), 8 outputs/lane ----------------
__global__ __launch_bounds__(256) void mm1_kernel(const float* __restrict__ x,
                                                  const float* __restrict__ W,
                                                  const float* __restrict__ dis,
                                                  unsigned short* __restrict__ y) {
    __shared__ float Ws[128 * 64];
    __shared__ float xs[4][8][132];
    int t = threadIdx.x;
    for (int i = t; i < 128 * 64; i += 256) Ws[i] = W[i];
    int wave = t >> 6, lane = t & 63;
    int nsub = lane >> 3;            // 8 nodes per wave
    int o8 = (lane & 7) * 8;         // 8 output cols per lane
    int base = blockIdx.x * 32 + wave * 8;   // 3125 blocks * 32 = 100000 exact
#pragma unroll
    for (int r = 0; r < 8; ++r) {
        xs[wave][r][lane] = x[(size_t)(base + r) * 128 + lane];
        xs[wave][r][lane + 64] = x[(size_t)(base + r) * 128 + 64 + lane];
    }
    __syncthreads();
    float acc[8] = {0, 0, 0, 0, 0, 0, 0, 0};
#pragma unroll 16
    for (int k = 0; k < 128; ++k) {
        float a = xs[wave][nsub][k];
        const float4 w0 = *(const float4*)&Ws[k * 64 + o8];
        const float4 w1 = *(const float4*)&Ws[k * 64 + o8 + 4];
        acc[0] = fmaf(a, w0.x, acc[0]); acc[1] = fmaf(a, w0.y, acc[1]);
        acc[2] = fmaf(a, w0.z, acc[2]); acc[3] = fmaf(a, w0.w, acc[3]);
        acc[4] = fmaf(a, w1.x, acc[4]); acc[5] = fmaf(a, w1.y, acc[5]);
        acc[6] = fmaf(a, w1.z, acc[6]); acc[7] = fmaf(a, w1.w, acc[7]);
    }
    float sc = dis[base + nsub];
    uint4 o;
    o.x = pack2(acc[0] * sc, acc[1] * sc);
    o.y = pack2(acc[2] * sc, acc[3] * sc);
    o.z = pack2(acc[4] * sc, acc[5] * sc);
    o.w = pack2(acc[6] * sc, acc[7] * sc);
    *(uint4*)&y[(size_t)(base + nsub) * 64 + o8] = o;
}

// ---------------- matmul 2: ys2 = bf16(dis * (h @ W2)), h bf16 ----------------
__global__ __launch_bounds__(256) void mm2_kernel(const unsigned short* __restrict__ h,
                                                  const float* __restrict__ W,
                                                  const float* __restrict__ dis,
                                                  unsigned short* __restrict__ y) {
    __shared__ float Ws[64 * 32];
    __shared__ float hs[4][8][68];
    int t = threadIdx.x;
    for (int i = t; i < 64 * 32; i += 256) Ws[i] = W[i];
    int wave = t >> 6, lane = t & 63;
    int nsub = lane >> 3;
    int o4 = (lane & 7) * 4;
    int base = blockIdx.x * 32 + wave * 8;
    const unsigned* h2 = (const unsigned*)h;   // 2 bf16 per uint, row = 32 uints
#pragma unroll
    for (int rr = 0; rr < 4; ++rr) {
        int r = rr * 2 + (lane >> 5);
        unsigned u = h2[(size_t)(base + r) * 32 + (lane & 31)];
        hs[wave][r][(lane & 31) * 2] = lo_f(u);
        hs[wave][r][(lane & 31) * 2 + 1] = hi_f(u);
    }
    __syncthreads();
    float4 acc = {0.f, 0.f, 0.f, 0.f};
#pragma unroll 16
    for (int k = 0; k < 64; ++k) {
        float a = hs[wave][nsub][k];
        const float4 w = *(const float4*)&Ws[k * 32 + o4];
        acc.x = fmaf(a, w.x, acc.x);
        acc.y = fmaf(a, w.y, acc.y);
        acc.z = fmaf(a, w.z, acc.z);
        acc.w = fmaf(a, w.w, acc.w);
    }
    float sc = dis[base + nsub];
    ushort4 o;
    o.x = bf16_of(acc.x * sc); o.y = bf16_of(acc.y * sc);
    o.z = bf16_of(acc.z * sc); o.w = bf16_of(acc.w * sc);
    *(ushort4*)&y[(size_t)(base + nsub) * 32 + o4] = o;
}

// ---------------- fused gather-aggregate, dim 64 bf16 -> h bf16, unroll 8 ----------------
__global__ __launch_bounds__(256) void agg64_kernel(const uint4* __restrict__ ys4,
                                                    const float* __restrict__ dis,
                                                    const int* __restrict__ offset,
                                                    const int* __restrict__ csr_src,
                                                    const float* __restrict__ b,
                                                    uint4* __restrict__ h4) {
    int tid = blockIdx.x * 256 + threadIdx.x;
    int nd = tid >> 3, c = tid & 7;
    if (nd >= NN) return;
    int start = offset[nd], end = offset[nd + 1];
    float acc[8] = {0, 0, 0, 0, 0, 0, 0, 0};
    acc8(acc, ys4[(size_t)nd * 8 + c]);  // self-loop term
    int i = start;
    int n8 = start + ((end - start) & ~7);
    for (; i < n8; i += 8) {
        int s0 = csr_src[i],     s1 = csr_src[i + 1], s2 = csr_src[i + 2], s3 = csr_src[i + 3];
        int s4 = csr_src[i + 4], s5 = csr_src[i + 5], s6 = csr_src[i + 6], s7 = csr_src[i + 7];
        uint4 r0 = ys4[(size_t)s0 * 8 + c];
        uint4 r1 = ys4[(size_t)s1 * 8 + c];
        uint4 r2 = ys4[(size_t)s2 * 8 + c];
        uint4 r3 = ys4[(size_t)s3 * 8 + c];
        uint4 r4 = ys4[(size_t)s4 * 8 + c];
        uint4 r5 = ys4[(size_t)s5 * 8 + c];
        uint4 r6 = ys4[(size_t)s6 * 8 + c];
        uint4 r7 = ys4[(size_t)s7 * 8 + c];
        acc8(acc, r0); acc8(acc, r1); acc8(acc, r2); acc8(acc, r3);
        acc8(acc, r4); acc8(acc, r5); acc8(acc, r6); acc8(acc, r7);
    }
    for (; i < end; ++i) acc8(acc, ys4[(size_t)csr_src[i] * 8 + c]);
    float ds = dis[nd];
    const float4 bv0 = *(const float4*)&b[c * 8];
    const float4 bv1 = *(const float4*)&b[c * 8 + 4];
    uint4 o;
    o.x = pack2(fmaxf(fmaf(ds, acc[0], bv0.x), 0.f), fmaxf(fmaf(ds, acc[1], bv0.y), 0.f));
    o.y = pack2(fmaxf(fmaf(ds, acc[2], bv0.z), 0.f), fmaxf(fmaf(ds, acc[3], bv0.w), 0.f));
    o.z = pack2(fmaxf(fmaf(ds, acc[4], bv1.x), 0.f), fmaxf(fmaf(ds, acc[5], bv1.y), 0.f));
    o.w = pack2(fmaxf(fmaf(ds, acc[6], bv1.z), 0.f), fmaxf(fmaf(ds, acc[7], bv1.w), 0.f));
    h4[(size_t)nd * 8 + c] = o;
}

// ---------------- fused gather-aggregate, dim 32 bf16 -> z bf16, unroll 8 ----------------
__global__ __launch_bounds__(256) void agg32_kernel(const uint4* __restrict__ ys4,
                                                    const float* __restrict__ dis,
                                                    const int* __restrict__ offset,
                                                    const int* __restrict__ csr_src,
                                                    const float* __restrict__ b,
                                                    uint4* __restrict__ z4) {
    int tid = blockIdx.x * 256 + threadIdx.x;
    int nd = tid >> 2, c = tid & 3;
    if (nd >= NN) return;
    int start = offset[nd], end = offset[nd + 1];
    float acc[8] = {0, 0, 0, 0, 0, 0, 0, 0};
    acc8(acc, ys4[(size_t)nd * 4 + c]);
    int i = start;
    int n8 = start + ((end - start) & ~7);
    for (; i < n8; i += 8) {
        int s0 = csr_src[i],     s1 = csr_src[i + 1], s2 = csr_src[i + 2], s3 = csr_src[i + 3];
        int s4 = csr_src[i + 4], s5 = csr_src[i + 5], s6 = csr_src[i + 6], s7 = csr_src[i + 7];
        uint4 r0 = ys4[(size_t)s0 * 4 + c];
        uint4 r1 = ys4[(size_t)s1 * 4 + c];
        uint4 r2 = ys4[(size_t)s2 * 4 + c];
        uint4 r3 = ys4[(size_t)s3 * 4 + c];
        uint4 r4 = ys4[(size_t)s4 * 4 + c];
        uint4 r5 = ys4[(size_t)s5 * 4 + c];
        uint4 r6 = ys4[(size_t)s6 * 4 + c];
        uint4 r7 = ys4[(size_t)s7 * 4 + c];
        acc8(acc, r0); acc8(acc, r1); acc8(acc, r2); acc8(acc, r3);
        acc8(acc, r4); acc8(acc, r5); acc8(acc, r6); acc8(acc, r7);
    }
    for (; i < end; ++i) acc8(acc, ys4[(size_t)csr_src[i] * 4 + c]);
    float ds = dis[nd];
    const float4 bv0 = *(const float4*)&b[c * 8];
    const float4 bv1 = *(const float4*)&b[c * 8 + 4];
    uint4 o;
    o.x = pack2(fmaf(ds, acc[0], bv0.x), fmaf(ds, acc[1], bv0.y));
    o.y = pack2(fmaf(ds, acc[2], bv0.z), fmaf(ds, acc[3], bv0.w));
    o.z = pack2(fmaf(ds, acc[4], bv1.x), fmaf(ds, acc[5], bv1.y));
    o.w = pack2(fmaf(ds, acc[6], bv1.z), fmaf(ds, acc[7], bv1.w));
    z4[(size_t)nd * 4 + c] = o;
}

// ---------------- decode: sigmoid(dot(z[src], z[dst])), 4 lanes/edge, bf16 z ---------
__global__ __launch_bounds__(256) void decode_kernel(const uint4* __restrict__ z4,
                                                     const int* __restrict__ src,
                                                     const int* __restrict__ dst,
                                                     float* __restrict__ out) {
    int tid = blockIdx.x * 256 + threadIdx.x;
    int e = tid >> 2, k = tid & 3;
    if (e >= NE) return;
    int s = src[e], d = dst[e];
    uint4 ra = z4[(size_t)s * 4 + k];
    uint4 rb = z4[(size_t)d * 4 + k];
    float acc;
    acc  = lo_f(ra.x) * lo_f(rb.x) + hi_f(ra.x) * hi_f(rb.x);
    acc += lo_f(ra.y) * lo_f(rb.y) + hi_f(ra.y) * hi_f(rb.y);
    acc += lo_f(ra.z) * lo_f(rb.z) + hi_f(ra.z) * hi_f(rb.z);
    acc += lo_f(ra.w) * lo_f(rb.w) + hi_f(ra.w) * hi_f(rb.w);
#pragma unroll
    for (int m = 2; m >= 1; m >>= 1) acc += __shfl_xor(acc, m, 4);
    if (k == 0) out[e] = 1.0f / (1.0f + expf(-acc));
}

// ---------------- launcher ----------------
extern "C" void kernel_launch(void* const* d_in, const int* in_sizes, int n_in,
                              void* d_out, int out_size, void* d_ws, size_t ws_size,
                              hipStream_t stream) {
    const float* emb = (const float*)d_in[0];
    const float* W1  = (const float*)d_in[1];
    const float* b1  = (const float*)d_in[2];
    const float* W2  = (const float*)d_in[3];
    const float* b2  = (const float*)d_in[4];
    const int*   ei  = (const int*)d_in[5];
    const int* src = ei;
    const int* dst = ei + NE;
    float* out = (float*)d_out;

    // workspace layout
    char* w = (char*)d_ws;
    int*   offset      = (int*)w;           w += (size_t)NPAD * 4;
    float* dis         = (float*)w;         w += (size_t)NPAD * 4;
    int*   bucket_base = (int*)w;           w += 1024;
    int*   totals      = (int*)w;           w += 1024;
    int*   blkhist     = (int*)w;           w += 307200;                  // NB*NBLK ints
    int*   csr_src     = (int*)w;           w += (size_t)NE * 4;          // 12.8MB
    int*   staged      = (int*)w;           w += (size_t)NE * 4;          // 12.8MB packed
    unsigned short* ysbuf = (unsigned short*)w; w += (size_t)NN * 64 * 2; // 12.8MB bf16
    unsigned short* h  = (unsigned short*)w;                              // 12.8MB bf16
    unsigned short* ys1 = ysbuf;
    unsigned short* ys2 = ysbuf;                       // overlays dead ys1
    unsigned short* z   = ysbuf + (size_t)NN * 32;     // second half of ysbuf

    // CSR build — LDS atomics only, contiguous staged writes
    hist_kernel<<<NBLK, 256, 0, stream>>>(dst, blkhist);
    scanA_kernel<<<NB, 64, 0, stream>>>(blkhist, totals);
    scanB_kernel<<<1, 256, 0, stream>>>(totals, bucket_base);
    scatter_kernel<<<NBLK, 256, 0, stream>>>(src, dst, blkhist, bucket_base, staged);
    fine_kernel<<<NB, 256, 0, stream>>>(staged, bucket_base, offset, dis, csr_src);

    // layer 1
    mm1_kernel<<<NN / 32, 256, 0, stream>>>(emb, W1, dis, ys1);
    agg64_kernel<<<(NN * 8) / 256, 256, 0, stream>>>((const uint4*)ys1, dis, offset, csr_src, b1, (uint4*)h);

    // layer 2
    mm2_kernel<<<NN / 32, 256, 0, stream>>>(h, W2, dis, ys2);
    agg32_kernel<<<(NN * 4 + 255) / 256, 256, 0, stream>>>((const uint4*)ys2, dis, offset, csr_src, b2, (uint4*)z);

    // decode
    decode_kernel<<<(NE * 4) / 256, 256, 0, stream>>>((const uint4*)z, src, dst, out);
}

// Round 6
// 363.285 us; speedup vs baseline: 12.6708x; 1.0963x over previous
//
#include <hip/hip_runtime.h>
#include <hip/hip_bf16.h>
#include <math.h>

#define NN 100000
#define NE 3200000
#define NPAD 100096
#define NB 196        // buckets: dst>>9, 512 nodes each
#define BN 512        // nodes per bucket
#define EPB 8192      // edges per block in hist/scatter passes
#define NBLK 391      // ceil(NE/EPB)

typedef __attribute__((ext_vector_type(8))) short short8;
typedef __attribute__((ext_vector_type(4))) float floatx4;

// ---------------- bf16 helpers (storage bf16, math fp32) ----------------
__device__ __forceinline__ unsigned short bf16_of(float x) {
    __hip_bfloat16 h = __float2bfloat16(x);  // RNE
    return *(unsigned short*)&h;
}
__device__ __forceinline__ unsigned pack2(float a, float b) {
    return (unsigned)bf16_of(a) | ((unsigned)bf16_of(b) << 16);
}
__device__ __forceinline__ float lo_f(unsigned u) { return __uint_as_float(u << 16); }
__device__ __forceinline__ float hi_f(unsigned u) { return __uint_as_float(u & 0xffff0000u); }
__device__ __forceinline__ void acc8(float* a, uint4 r) {
    a[0] += lo_f(r.x); a[1] += hi_f(r.x);
    a[2] += lo_f(r.y); a[3] += hi_f(r.y);
    a[4] += lo_f(r.z); a[5] += hi_f(r.z);
    a[6] += lo_f(r.w); a[7] += hi_f(r.w);
}

// ---------------- pass A: per-block bucket histogram (bucket-major out) ----------------
__global__ __launch_bounds__(256) void hist_kernel(const int* __restrict__ dst,
                                                   int* __restrict__ blkhist) {
    __shared__ int cnt[NB];
    int t = threadIdx.x;
    for (int i = t; i < NB; i += 256) cnt[i] = 0;
    __syncthreads();
    int e0 = blockIdx.x * EPB;
    int e1 = min(e0 + EPB, NE);
    for (int e = e0 + t; e < e1; e += 256) atomicAdd(&cnt[dst[e] >> 9], 1);
    __syncthreads();
    for (int i = t; i < NB; i += 256) blkhist[i * NBLK + blockIdx.x] = cnt[i];
}

// ---------------- pass B1: per-bucket exclusive scan along blocks ----------------
__global__ __launch_bounds__(64) void scanA_kernel(int* __restrict__ blkhist,
                                                   int* __restrict__ totals) {
    int j = blockIdx.x, lane = threadIdx.x;
    int base = j * NBLK;
    int carry = 0;
    for (int c = 0; c < NBLK; c += 64) {
        int b = c + lane;
        int v = (b < NBLK) ? blkhist[base + b] : 0;
        int inc = v;
#pragma unroll
        for (int m = 1; m < 64; m <<= 1) {
            int u = __shfl_up(inc, m, 64);
            if (lane >= m) inc += u;
        }
        if (b < NBLK) blkhist[base + b] = carry + inc - v;
        carry += __shfl(inc, 63, 64);
    }
    if (lane == 0) totals[j] = carry;
}

// ---------------- pass B2: bucket bases ----------------
__global__ __launch_bounds__(256) void scanB_kernel(const int* __restrict__ totals,
                                                    int* __restrict__ bucket_base) {
    __shared__ int sm[NB];
    int t = threadIdx.x;
    if (t < NB) sm[t] = totals[t];
    __syncthreads();
    if (t == 0) {
        int r = 0;
        for (int i = 0; i < NB; ++i) { bucket_base[i] = r; r += sm[i]; }
        bucket_base[NB] = r;
    }
}

// ---------------- pass C: LDS-staged scatter -> contiguous run writes ----------------
__global__ __launch_bounds__(256) void scatter_kernel(const int* __restrict__ src,
                                                      const int* __restrict__ dst,
                                                      const int* __restrict__ blkhist,
                                                      const int* __restrict__ bucket_base,
                                                      int* __restrict__ staged) {
    __shared__ int cnt[NB];
    __shared__ int lbase[NB + 1];
    __shared__ int gbase[NB];
    __shared__ int sbuf[EPB];             // 32KB
    __shared__ unsigned char sbkt[EPB];   // 8KB: bucket id per slot
    int t = threadIdx.x;
    for (int i = t; i < NB; i += 256) cnt[i] = 0;
    __syncthreads();
    int e0 = blockIdx.x * EPB;
    int e1 = min(e0 + EPB, NE);
    int cn = e1 - e0;
    for (int e = e0 + t; e < e1; e += 256) atomicAdd(&cnt[dst[e] >> 9], 1);
    __syncthreads();
    if (t < 64) {  // exclusive scan of 196 counts, 4 per lane
        int v[4]; int s = 0;
#pragma unroll
        for (int k = 0; k < 4; ++k) { int idx = t * 4 + k; v[k] = (idx < NB) ? cnt[idx] : 0; s += v[k]; }
        int inc = s;
#pragma unroll
        for (int m = 1; m < 64; m <<= 1) {
            int u = __shfl_up(inc, m, 64);
            if (t >= m) inc += u;
        }
        int run = inc - s;
#pragma unroll
        for (int k = 0; k < 4; ++k) { int idx = t * 4 + k; if (idx < NB) lbase[idx] = run; run += v[k]; }
        if (t == 63) lbase[NB] = inc;  // == cn
    }
    __syncthreads();
    for (int i = t; i < NB; i += 256) {
        gbase[i] = bucket_base[i] + blkhist[i * NBLK + blockIdx.x];
        cnt[i] = lbase[i];            // rank cursors
    }
    __syncthreads();
    for (int e = e0 + t; e < e1; e += 256) {
        int s = src[e], d = dst[e];
        int bk = d >> 9;
        int r = atomicAdd(&cnt[bk], 1);     // LDS atomic
        sbuf[r] = (s << 9) | (d & (BN - 1));
        sbkt[r] = (unsigned char)bk;
    }
    __syncthreads();
    for (int i = t; i < cn; i += 256) {     // contiguous run write-out
        int bk = sbkt[i];
        staged[gbase[bk] + i - lbase[bk]] = sbuf[i];
    }
}

// ---------------- pass D: per-bucket fine counting sort + offsets + dis ----------------
__global__ __launch_bounds__(256) void fine_kernel(const int* __restrict__ staged,
                                                   const int* __restrict__ bucket_base,
                                                   int* __restrict__ offset,
                                                   float* __restrict__ dis,
                                                   int* __restrict__ csr_src) {
    __shared__ int hist[BN];
    __shared__ int offs[BN];
    __shared__ int cur[BN];
    int t = threadIdx.x, j = blockIdx.x;
    int bb = bucket_base[j], be = bucket_base[j + 1];
    for (int i = t; i < BN; i += 256) hist[i] = 0;
    __syncthreads();
    for (int e = bb + t; e < be; e += 256) atomicAdd(&hist[staged[e] & (BN - 1)], 1);
    __syncthreads();
    if (t < 64) {  // wave0: exclusive scan of 512 counts
        int v[8]; int s = 0;
#pragma unroll
        for (int k = 0; k < 8; ++k) { v[k] = hist[t * 8 + k]; s += v[k]; }
        int inc = s;
#pragma unroll
        for (int m = 1; m < 64; m <<= 1) {
            int u = __shfl_up(inc, m, 64);
            if (t >= m) inc += u;
        }
        int run = inc - s;
#pragma unroll
        for (int k = 0; k < 8; ++k) { offs[t * 8 + k] = run; run += v[k]; }
    }
    __syncthreads();
    for (int l = t; l < BN; l += 256) {
        cur[l] = offs[l];
        int n = j * BN + l;
        if (n < NN) {
            offset[n] = bb + offs[l];
            dis[n] = rsqrtf((float)hist[l] + 1.0f);
        }
    }
    if (j == NB - 1 && t == 0) offset[NN] = NE;
    __syncthreads();
    for (int e = bb + t; e < be; e += 256) {
        int p = staged[e];
        int r = atomicAdd(&cur[p & (BN - 1)], 1);  // LDS atomic
        csr_src[bb + r] = p >> 9;
    }
}

// ---------------- matmul 1 (MFMA): ys1 = bf16(dis * (x @ W1)) ----------------
// Tiles of 16 nodes; N=64 -> 4 col-tiles; K=128 -> 4 k-steps of 32.
// B-fragments (W) live in VGPRs; A loaded from global, cvt to bf16 in-reg.
__global__ __launch_bounds__(256) void mm1_kernel(const float* __restrict__ x,
                                                  const float* __restrict__ W,
                                                  const float* __restrict__ dis,
                                                  unsigned short* __restrict__ y) {
    __shared__ unsigned short Wt[64][136];  // W^T bf16: [n][k], pad 8 shorts
    int t = threadIdx.x;
    for (int i = t; i < 128 * 64; i += 256) {
        int k = i >> 6, n = i & 63;
        Wt[n][k] = bf16_of(W[i]);
    }
    __syncthreads();
    int wave = t >> 6, lane = t & 63;
    int quad = lane >> 4, n16 = lane & 15;
    short8 bfr[4][4];  // [kstep][coltile]: B[k=s*32+quad*8+j][n=tt*16+n16]
#pragma unroll
    for (int s = 0; s < 4; ++s)
#pragma unroll
        for (int tt = 0; tt < 4; ++tt)
            bfr[s][tt] = *(const short8*)&Wt[tt * 16 + n16][s * 32 + quad * 8];
    int tile0 = (blockIdx.x * 4 + wave) * 4;   // 391 blocks x 4 waves x 4 tiles >= 6250
#pragma unroll 1
    for (int it = 0; it < 4; ++it) {
        int tile = tile0 + it;
        if (tile >= 6250) break;
        int m0 = tile * 16;
        const float* xp = x + (size_t)(m0 + n16) * 128 + quad * 8;  // A row = m0+n16
        floatx4 acc0 = {0,0,0,0}, acc1 = {0,0,0,0}, acc2 = {0,0,0,0}, acc3 = {0,0,0,0};
#pragma unroll
        for (int s = 0; s < 4; ++s) {
            float4 lo = *(const float4*)(xp + s * 32);
            float4 hi = *(const float4*)(xp + s * 32 + 4);
            short8 a;
            a[0] = (short)bf16_of(lo.x); a[1] = (short)bf16_of(lo.y);
            a[2] = (short)bf16_of(lo.z); a[3] = (short)bf16_of(lo.w);
            a[4] = (short)bf16_of(hi.x); a[5] = (short)bf16_of(hi.y);
            a[6] = (short)bf16_of(hi.z); a[7] = (short)bf16_of(hi.w);
            acc0 = __builtin_amdgcn_mfma_f32_16x16x32_bf16(a, bfr[s][0], acc0, 0, 0, 0);
            acc1 = __builtin_amdgcn_mfma_f32_16x16x32_bf16(a, bfr[s][1], acc1, 0, 0, 0);
            acc2 = __builtin_amdgcn_mfma_f32_16x16x32_bf16(a, bfr[s][2], acc2, 0, 0, 0);
            acc3 = __builtin_amdgcn_mfma_f32_16x16x32_bf16(a, bfr[s][3], acc3, 0, 0, 0);
        }
        // D: row = m0 + quad*4 + r, col = tt*16 + n16
#pragma unroll
        for (int r = 0; r < 4; ++r) {
            int ro = m0 + quad * 4 + r;
            float sc = dis[ro];
            unsigned short* yp = y + (size_t)ro * 64 + n16;
            yp[0]  = bf16_of(acc0[r] * sc);
            yp[16] = bf16_of(acc1[r] * sc);
            yp[32] = bf16_of(acc2[r] * sc);
            yp[48] = bf16_of(acc3[r] * sc);
        }
    }
}

// ---------------- matmul 2 (MFMA): ys2 = bf16(dis * (h @ W2)), h bf16 ----------------
// N=32 -> 2 col-tiles; K=64 -> 2 k-steps.
__global__ __launch_bounds__(256) void mm2_kernel(const unsigned short* __restrict__ h,
                                                  const float* __restrict__ W,
                                                  const float* __restrict__ dis,
                                                  unsigned short* __restrict__ y) {
    __shared__ unsigned short Wt[32][72];  // W^T bf16: [n][k], pad 8
    int t = threadIdx.x;
    for (int i = t; i < 64 * 32; i += 256) {
        int k = i >> 5, n = i & 31;
        Wt[n][k] = bf16_of(W[i]);
    }
    __syncthreads();
    int wave = t >> 6, lane = t & 63;
    int quad = lane >> 4, n16 = lane & 15;
    short8 bfr[2][2];
#pragma unroll
    for (int s = 0; s < 2; ++s)
#pragma unroll
        for (int tt = 0; tt < 2; ++tt)
            bfr[s][tt] = *(const short8*)&Wt[tt * 16 + n16][s * 32 + quad * 8];
    int tile0 = (blockIdx.x * 4 + wave) * 4;
#pragma unroll 1
    for (int it = 0; it < 4; ++it) {
        int tile = tile0 + it;
        if (tile >= 6250) break;
        int m0 = tile * 16;
        const unsigned short* hp = h + (size_t)(m0 + n16) * 64 + quad * 8;
        floatx4 acc0 = {0,0,0,0}, acc1 = {0,0,0,0};
#pragma unroll
        for (int s = 0; s < 2; ++s) {
            short8 a = *(const short8*)(hp + s * 32);
            acc0 = __builtin_amdgcn_mfma_f32_16x16x32_bf16(a, bfr[s][0], acc0, 0, 0, 0);
            acc1 = __builtin_amdgcn_mfma_f32_16x16x32_bf16(a, bfr[s][1], acc1, 0, 0, 0);
        }
#pragma unroll
        for (int r = 0; r < 4; ++r) {
            int ro = m0 + quad * 4 + r;
            float sc = dis[ro];
            unsigned short* yp = y + (size_t)ro * 32 + n16;
            yp[0]  = bf16_of(acc0[r] * sc);
            yp[16] = bf16_of(acc1[r] * sc);
        }
    }
}

// ---------------- fused gather-aggregate, dim 64 bf16 -> h bf16, unroll 8 ----------------
__global__ __launch_bounds__(256) void agg64_kernel(const uint4* __restrict__ ys4,
                                                    const float* __restrict__ dis,
                                                    const int* __restrict__ offset,
                                                    const int* __restrict__ csr_src,
                                                    const float* __restrict__ b,
                                                    uint4* __restrict__ h4) {
    int tid = blockIdx.x * 256 + threadIdx.x;
    int nd = tid >> 3, c = tid & 7;
    if (nd >= NN) return;
    int start = offset[nd], end = offset[nd + 1];
    float acc[8] = {0, 0, 0, 0, 0, 0, 0, 0};
    acc8(acc, ys4[(size_t)nd * 8 + c]);  // self-loop term
    int i = start;
    int n8 = start + ((end - start) & ~7);
    for (; i < n8; i += 8) {
        int s0 = csr_src[i],     s1 = csr_src[i + 1], s2 = csr_src[i + 2], s3 = csr_src[i + 3];
        int s4 = csr_src[i + 4], s5 = csr_src[i + 5], s6 = csr_src[i + 6], s7 = csr_src[i + 7];
        uint4 r0 = ys4[(size_t)s0 * 8 + c];
        uint4 r1 = ys4[(size_t)s1 * 8 + c];
        uint4 r2 = ys4[(size_t)s2 * 8 + c];
        uint4 r3 = ys4[(size_t)s3 * 8 + c];
        uint4 r4 = ys4[(size_t)s4 * 8 + c];
        uint4 r5 = ys4[(size_t)s5 * 8 + c];
        uint4 r6 = ys4[(size_t)s6 * 8 + c];
        uint4 r7 = ys4[(size_t)s7 * 8 + c];
        acc8(acc, r0); acc8(acc, r1); acc8(acc, r2); acc8(acc, r3);
        acc8(acc, r4); acc8(acc, r5); acc8(acc, r6); acc8(acc, r7);
    }
    for (; i < end; ++i) acc8(acc, ys4[(size_t)csr_src[i] * 8 + c]);
    float ds = dis[nd];
    const float4 bv0 = *(const float4*)&b[c * 8];
    const float4 bv1 = *(const float4*)&b[c * 8 + 4];
    uint4 o;
    o.x = pack2(fmaxf(fmaf(ds, acc[0], bv0.x), 0.f), fmaxf(fmaf(ds, acc[1], bv0.y), 0.f));
    o.y = pack2(fmaxf(fmaf(ds, acc[2], bv0.z), 0.f), fmaxf(fmaf(ds, acc[3], bv0.w), 0.f));
    o.z = pack2(fmaxf(fmaf(ds, acc[4], bv1.x), 0.f), fmaxf(fmaf(ds, acc[5], bv1.y), 0.f));
    o.w = pack2(fmaxf(fmaf(ds, acc[6], bv1.z), 0.f), fmaxf(fmaf(ds, acc[7], bv1.w), 0.f));
    h4[(size_t)nd * 8 + c] = o;
}

// ---------------- fused gather-aggregate, dim 32 bf16 -> z bf16, unroll 8 ----------------
__global__ __launch_bounds__(256) void agg32_kernel(const uint4* __restrict__ ys4,
                                                    const float* __restrict__ dis,
                                                    const int* __restrict__ offset,
                                                    const int* __restrict__ csr_src,
                                                    const float* __restrict__ b,
                                                    uint4* __restrict__ z4) {
    int tid = blockIdx.x * 256 + threadIdx.x;
    int nd = tid >> 2, c = tid & 3;
    if (nd >= NN) return;
    int start = offset[nd], end = offset[nd + 1];
    float acc[8] = {0, 0, 0, 0, 0, 0, 0, 0};
    acc8(acc, ys4[(size_t)nd * 4 + c]);
    int i = start;
    int n8 = start + ((end - start) & ~7);
    for (; i < n8; i += 8) {
        int s0 = csr_src[i],     s1 = csr_src[i + 1], s2 = csr_src[i + 2], s3 = csr_src[i + 3];
        int s4 = csr_src[i + 4], s5 = csr_src[i + 5], s6 = csr_src[i + 6], s7 = csr_src[i + 7];
        uint4 r0 = ys4[(size_t)s0 * 4 + c];
        uint4 r1 = ys4[(size_t)s1 * 4 + c];
        uint4 r2 = ys4[(size_t)s2 * 4 + c];
        uint4 r3 = ys4[(size_t)s3 * 4 + c];
        uint4 r4 = ys4[(size_t)s4 * 4 + c];
        uint4 r5 = ys4[(size_t)s5 * 4 + c];
        uint4 r6 = ys4[(size_t)s6 * 4 + c];
        uint4 r7 = ys4[(size_t)s7 * 4 + c];
        acc8(acc, r0); acc8(acc, r1); acc8(acc, r2); acc8(acc, r3);
        acc8(acc, r4); acc8(acc, r5); acc8(acc, r6); acc8(acc, r7);
    }
    for (; i < end; ++i) acc8(acc, ys4[(size_t)csr_src[i] * 4 + c]);
    float ds = dis[nd];
    const float4 bv0 = *(const float4*)&b[c * 8];
    const float4 bv1 = *(const float4*)&b[c * 8 + 4];
    uint4 o;
    o.x = pack2(fmaf(ds, acc[0], bv0.x), fmaf(ds, acc[1], bv0.y));
    o.y = pack2(fmaf(ds, acc[2], bv0.z), fmaf(ds, acc[3], bv0.w));
    o.z = pack2(fmaf(ds, acc[4], bv1.x), fmaf(ds, acc[5], bv1.y));
    o.w = pack2(fmaf(ds, acc[6], bv1.z), fmaf(ds, acc[7], bv1.w));
    z4[(size_t)nd * 4 + c] = o;
}

// ---------------- decode: sigmoid(dot(z[src], z[dst])), 4 lanes/edge, bf16 z ---------
__global__ __launch_bounds__(256) void decode_kernel(const uint4* __restrict__ z4,
                                                     const int* __restrict__ src,
                                                     const int* __restrict__ dst,
                                                     float* __restrict__ out) {
    int tid = blockIdx.x * 256 + threadIdx.x;
    int e = tid >> 2, k = tid & 3;
    if (e >= NE) return;
    int s = src[e], d = dst[e];
    uint4 ra = z4[(size_t)s * 4 + k];
    uint4 rb = z4[(size_t)d * 4 + k];
    float acc;
    acc  = lo_f(ra.x) * lo_f(rb.x) + hi_f(ra.x) * hi_f(rb.x);
    acc += lo_f(ra.y) * lo_f(rb.y) + hi_f(ra.y) * hi_f(rb.y);
    acc += lo_f(ra.z) * lo_f(rb.z) + hi_f(ra.z) * hi_f(rb.z);
    acc += lo_f(ra.w) * lo_f(rb.w) + hi_f(ra.w) * hi_f(rb.w);
#pragma unroll
    for (int m = 2; m >= 1; m >>= 1) acc += __shfl_xor(acc, m, 4);
    if (k == 0) out[e] = 1.0f / (1.0f + expf(-acc));
}

// ---------------- launcher ----------------
extern "C" void kernel_launch(void* const* d_in, const int* in_sizes, int n_in,
                              void* d_out, int out_size, void* d_ws, size_t ws_size,
                              hipStream_t stream) {
    const float* emb = (const float*)d_in[0];
    const float* W1  = (const float*)d_in[1];
    const float* b1  = (const float*)d_in[2];
    const float* W2  = (const float*)d_in[3];
    const float* b2  = (const float*)d_in[4];
    const int*   ei  = (const int*)d_in[5];
    const int* src = ei;
    const int* dst = ei + NE;
    float* out = (float*)d_out;

    // workspace layout
    char* w = (char*)d_ws;
    int*   offset      = (int*)w;           w += (size_t)NPAD * 4;
    float* dis         = (float*)w;         w += (size_t)NPAD * 4;
    int*   bucket_base = (int*)w;           w += 1024;
    int*   totals      = (int*)w;           w += 1024;
    int*   blkhist     = (int*)w;           w += 307200;                  // NB*NBLK ints
    int*   csr_src     = (int*)w;           w += (size_t)NE * 4;          // 12.8MB
    int*   staged      = (int*)w;           w += (size_t)NE * 4;          // 12.8MB packed
    unsigned short* ysbuf = (unsigned short*)w; w += (size_t)NN * 64 * 2; // 12.8MB bf16
    unsigned short* h  = (unsigned short*)w;                              // 12.8MB bf16
    unsigned short* ys1 = ysbuf;
    unsigned short* ys2 = ysbuf;                       // overlays dead ys1
    unsigned short* z   = ysbuf + (size_t)NN * 32;     // second half of ysbuf

    // CSR build — LDS atomics only, contiguous staged writes
    hist_kernel<<<NBLK, 256, 0, stream>>>(dst, blkhist);
    scanA_kernel<<<NB, 64, 0, stream>>>(blkhist, totals);
    scanB_kernel<<<1, 256, 0, stream>>>(totals, bucket_base);
    scatter_kernel<<<NBLK, 256, 0, stream>>>(src, dst, blkhist, bucket_base, staged);
    fine_kernel<<<NB, 256, 0, stream>>>(staged, bucket_base, offset, dis, csr_src);

    // layer 1
    mm1_kernel<<<391, 256, 0, stream>>>(emb, W1, dis, ys1);
    agg64_kernel<<<(NN * 8) / 256, 256, 0, stream>>>((const uint4*)ys1, dis, offset, csr_src, b1, (uint4*)h);

    // layer 2
    mm2_kernel<<<391, 256, 0, stream>>>(h, W2, dis, ys2);
    agg32_kernel<<<(NN * 4 + 255) / 256, 256, 0, stream>>>((const uint4*)ys2, dis, offset, csr_src, b2, (uint4*)z);

    // decode
    decode_kernel<<<(NE * 4) / 256, 256, 0, stream>>>((const uint4*)z, src, dst, out);
}